// Round 6
// baseline (1300.999 us; speedup 1.0000x reference)
//
#include <hip/hip_runtime.h>
#include <math.h>

#define B_   4
#define M_   80
#define TMEL 63
#define R_   120
#define S_   240
#define Q_   256
#define NB_  16
#define L_   15872

typedef float  f32x4  __attribute__((ext_vector_type(4)));
typedef short  bf16x8 __attribute__((ext_vector_type(8)));
typedef short  short4_t __attribute__((ext_vector_type(4)));

__device__ __forceinline__ short f2bf(float x) {
  unsigned u = __builtin_bit_cast(unsigned, x);
  u += 0x7fffu + ((u >> 16) & 1u);
  return (short)(u >> 16);
}
__device__ __forceinline__ float bf2f(unsigned short s) {
  unsigned u = ((unsigned)s) << 16;
  return __builtin_bit_cast(float, u);
}

// ---------------------------------------------------------------------------
// melT[b][i][m] bf16  <-  mel[b][m][i] f32
// ---------------------------------------------------------------------------
__global__ __launch_bounds__(256) void prep_melT_kernel(
    const float* __restrict__ mel, short* __restrict__ melT)
{
  const int idx = blockIdx.x * 256 + threadIdx.x;
  if (idx >= B_ * TMEL * M_) return;
  const int m = idx % M_;
  const int i = (idx / M_) % TMEL;
  const int b = idx / (M_ * TMEL);
  melT[idx] = f2bf(mel[b * (M_ * TMEL) + m * TMEL + i]);
}

// ---------------------------------------------------------------------------
// Wup[phi][c][j*80+m] bf16: tap j <-> delta = dmin(phi)+j, q = 400+phi+256*delta
// ---------------------------------------------------------------------------
__global__ __launch_bounds__(256) void prep_wup_kernel(
    const float* __restrict__ w_up, short* __restrict__ Wup)
{
  __shared__ float T[M_][65];
  const int c  = blockIdx.x >> 4;
  const int j  = (blockIdx.x >> 2) & 3;
  const int fb = blockIdx.x & 3;
  for (int idx = threadIdx.x; idx < M_ * 64; idx += 256) {
    const int pl = idx & 63, m = idx >> 6;
    const int phi = fb * 64 + pl;
    const int dmin = (phi < 112) ? -1 : -2;
    const int dmax = (phi < 144) ? 1 : 0;
    const int delta = dmin + j;
    float v = 0.0f;
    if (delta <= dmax)
      v = w_up[m * (M_ * 800) + c * 800 + (400 + phi + 256 * delta)];
    T[m][pl] = v;
  }
  __syncthreads();
  for (int idx = threadIdx.x; idx < 64 * M_; idx += 256) {
    const int m = idx % M_, pl = idx / M_;
    const int phi = fb * 64 + pl;
    Wup[((size_t)phi * M_ + c) * 320 + j * 80 + m] = f2bf(T[m][pl]);
  }
}

// ---------------------------------------------------------------------------
// Upsample as per-phase MFMA GEMM -> condb[b][t][80] bf16
// ---------------------------------------------------------------------------
#define KPU 328

__global__ __launch_bounds__(256, 2) void upsample_mfma_kernel(
    const short* __restrict__ melT, const short* __restrict__ Wup,
    const float* __restrict__ b_up, short* __restrict__ condb)
{
  __shared__ __align__(16) short Xu[64 * KPU];
  const int tid = threadIdx.x;
  const int phi = blockIdx.x;
  const int r0 = blockIdx.y * 64;
  const int dmin = (phi < 112) ? -1 : -2;

  for (int idx = tid; idx < 2560; idx += 256) {
    const int v = idx % 10;
    const int j = (idx / 10) & 3;
    const int rl = idx / 40;
    const int rho = r0 + rl;
    const int b = rho / 62;
    const int n = rho - b * 62;
    const int i = n - (dmin + j);
    int4 val = make_int4(0, 0, 0, 0);
    if (b < B_ && i >= 0 && i < TMEL)
      val = *(const int4*)&melT[((size_t)b * TMEL + i) * M_ + v * 8];
    *(int4*)&Xu[rl * KPU + j * 80 + v * 8] = val;
  }
  __syncthreads();

  const int lane = tid & 63;
  const int wv = tid >> 6;
  const int col = lane & 15;
  const int quad = lane >> 4;
  const int kq = quad * 8;

  f32x4 acc[5];
#pragma unroll
  for (int i = 0; i < 5; ++i) acc[i] = (f32x4)(0.f);
#pragma unroll
  for (int ks = 0; ks < 10; ++ks) {
    bf16x8 a = *(const bf16x8*)&Xu[(wv * 16 + col) * KPU + ks * 32 + kq];
#pragma unroll
    for (int ct = 0; ct < 5; ++ct) {
      bf16x8 b = *(const bf16x8*)(Wup + ((size_t)phi * M_ + ct * 16 + col) * 320 + ks * 32 + kq);
      acc[ct] = __builtin_amdgcn_mfma_f32_16x16x32_bf16(a, b, acc[ct], 0, 0, 0);
    }
  }
#pragma unroll
  for (int ct = 0; ct < 5; ++ct) {
    const int c = ct * 16 + col;
    const float bc = b_up[c];
#pragma unroll
    for (int reg = 0; reg < 4; ++reg) {
      const int rho = r0 + wv * 16 + quad * 4 + reg;
      if (rho < 248) {
        const int b = rho / 62;
        const int n = rho - b * 62;
        const int t = phi + (n << 8);
        condb[((size_t)b * L_ + t) * M_ + c] = f2bf(acc[ct][reg] + bc);
      }
    }
  }
}

// res0[b][t][128] bf16
__global__ __launch_bounds__(256) void in_conv_kernel(
    const float* __restrict__ wav, const float* __restrict__ w_in,
    const float* __restrict__ b_in, short* __restrict__ res)
{
  const int idx = blockIdx.x * 256 + threadIdx.x;
  const int r = idx & 127;
  const int rem = idx >> 7;
  const int t = rem % L_;
  const int b = rem / L_;
  res[idx] = (r < R_) ? f2bf(w_in[r] * wav[b * L_ + t] + b_in[r]) : (short)0;
}

// ---------------------------------------------------------------------------
// Weight prepacks.  W1p layout (R5): f-channels in cp 0..119 (tiles 0-7),
// g-channels in cp 128..247 (tiles 8-15) -> wave wv computes f and g for the
// SAME channels in the same lane; gating needs no cross-lane shuffle.
// ---------------------------------------------------------------------------
__global__ __launch_bounds__(256) void prepack_w1_kernel(
    const float* __restrict__ wg, const float* __restrict__ wc,
    short* __restrict__ W1p)
{
  const int idx = blockIdx.x * 256 + threadIdx.x;   // 16*256*320
  const int k = idx % 320;
  const int cp = (idx / 320) % 256;
  const int i = idx / (320 * 256);
  int corig = -1;
  if (cp < 128) { if (cp < 120) corig = cp; }                 // f = rows 0..119
  else          { const int c = cp - 128; if (c < 120) corig = 120 + c; } // g
  float val = 0.0f;
  if (corig >= 0) {
    if (k < 120)      val = wg[((size_t)(i * 240 + corig) * 120 + k) * 2 + 0];
    else if (k < 240) val = wg[((size_t)(i * 240 + corig) * 120 + (k - 120)) * 2 + 1];
    else              val = wc[(size_t)(i * 240 + corig) * 80 + (k - 240)];
  }
  W1p[idx] = f2bf(val);
}

__global__ __launch_bounds__(256) void prepack_w2_kernel(
    const float* __restrict__ wsk, const float* __restrict__ wr,
    short* __restrict__ W2p)
{
  const int idx = blockIdx.x * 256 + threadIdx.x;   // 16*384*128
  const int k = idx % 128;
  const int sp = (idx / 128) % 384;
  const int i = idx / (128 * 384);
  float val = 0.0f;
  if (k < 120) {
    if (sp < 240)      val = wsk[(size_t)(i * 240 + sp) * 120 + k];
    else if (sp < 360) val = wr[(size_t)(i * 120 + (sp - 240)) * 120 + k];
  }
  W2p[idx] = f2bf(val);
}

__global__ __launch_bounds__(256) void prepack_rest_kernel(
    const float* __restrict__ wh1, const float* __restrict__ wh2,
    const float* __restrict__ bg, const float* __restrict__ bc,
    const float* __restrict__ bs, const float* __restrict__ br,
    short* __restrict__ Wh1p, short* __restrict__ Wh2p,
    float* __restrict__ bias1p, float* __restrict__ bias2p)
{
  const int idx = blockIdx.x * 256 + threadIdx.x;   // 141312
  if (idx < 65536) {
    const int q = idx >> 8, k = idx & 255;
    Wh1p[idx] = f2bf(k < 240 ? wh1[q * 240 + k] : 0.0f);
  } else if (idx < 131072) {
    Wh2p[idx - 65536] = f2bf(wh2[idx - 65536]);
  } else if (idx < 135168) {
    // bias1p[i][cp 0..255]: cp<128 -> f bias, cp>=128 -> g bias (R5 layout)
    const int j = idx - 131072;
    const int i = j >> 8, cp = j & 255;
    float v = 0.0f;
    if (cp < 128) { if (cp < 120) v = bg[i * 240 + cp] + bc[i * 240 + cp]; }
    else { const int c = cp - 128; if (c < 120) v = bg[i * 240 + 120 + c] + bc[i * 240 + 120 + c]; }
    bias1p[j] = v;
  } else if (idx < 141312) {
    const int j = idx - 135168;
    const int i = j / 384, sp = j % 384;
    float v = 0.0f;
    if (sp < 240)      v = bs[i * 240 + sp];
    else if (sp < 360) v = br[i * 120 + (sp - 240)];
    bias2p[j] = v;
  }
}

// ---------------------------------------------------------------------------
// MFMA residual block. 512 threads / 8 waves.
// R6: 2 tiles per WG, software-pipelined (grid 992 -> 496 WGs).
// Theory: R5 counters showed every pipe <35% busy with dur ~= SUM of pipe
// times -> phase-synchronized serialization (all WGs march through identical
// barrier phases in lockstep). Fix: while tile1 runs GEMM2/epilogue/RMW, the
// WG issues tile2's staging loads (res rows + condb) into registers; after
// tile1's RMW frees Xs, ds_write them and run tile2. Memory is now in flight
// under compute within each WG (T14 at tile granularity). Also halves
// synchronized dispatch cold-starts/tails.
// Per-tile skips-old prefetch stays at its R5 slot (pre-GEMM2).
// Kept: XOR-swizzled Xs (40960 B), Zs-in-tap0/cond overlay preserving tap1,
// f/g-split in-lane gating, LDS res_old epilogue, XCD-chunked swizzle
// (496 = 8 x 62 bijective), bf16 res stream, setprio, launch_bounds (512,4).
// ---------------------------------------------------------------------------
#define KP1 320
#define SGP 248
#define NTILE (L_ / 64)          // 248  (head swizzle)
#define NWG   (NTILE * B_)       // 992
#define CPX   (NWG / 8)          // 124
#define NPAIR (L_ / 128)         // 124 tile-pairs per batch
#define NWGB  (NPAIR * B_)       // 496 block WGs
#define CPXB  (NWGB / 8)         // 62

__device__ __forceinline__ int xswz(int row, int k) {
  return row * KP1 + (k ^ ((row & 7) << 3));
}

// G1 -> gate -> (skips prefetch) -> G2 -> [PREF: issue next-tile loads]
// -> phaseA(res store) -> phaseB(SG) -> RMW. Entry: Xs staged + barrier done.
// Exit: after RMW, NO trailing barrier (caller barriers before touching Xs).
template<int PREF>
__device__ __forceinline__ void tile_body(
    short* __restrict__ Xs, const int tid, const int wv, const int col,
    const int quad, const int kq, const int bb, const int t0,
    const int d, const int dd, const int nr, const int first,
    const short* __restrict__ res_in, short* __restrict__ res_out,
    unsigned short* __restrict__ skips, const short* __restrict__ condb,
    const short* __restrict__ W1, const short* __restrict__ W2,
    const float* __restrict__ bias1, const float* __restrict__ bias2,
    int4* __restrict__ rv, int4* __restrict__ cv, const int t0n)
{
  // ---- GEMM1: ct=0 -> f-tile wv, ct=1 -> g-tile 8+wv (same channels) ----
  f32x4 acc[4][2];
#pragma unroll
  for (int a = 0; a < 4; ++a)
#pragma unroll
    for (int b = 0; b < 2; ++b) acc[a][b] = (f32x4)(0.f);
  __builtin_amdgcn_s_setprio(1);
#pragma unroll
  for (int ks = 0; ks < 10; ++ks) {
    bf16x8 av[4];
#pragma unroll
    for (int tf = 0; tf < 4; ++tf)
      av[tf] = *(const bf16x8*)&Xs[xswz(tf * 16 + col, ks * 32 + kq)];
#pragma unroll
    for (int ct = 0; ct < 2; ++ct) {
      const int cpt = ((ct == 0) ? wv : (wv + 8)) * 16 + col;
      bf16x8 b = *(const bf16x8*)(W1 + cpt * 320 + ks * 32 + kq);
#pragma unroll
      for (int tf = 0; tf < 4; ++tf)
        acc[tf][ct] = __builtin_amdgcn_mfma_f32_16x16x32_bf16(av[tf], b, acc[tf][ct], 0, 0, 0);
    }
  }
  __builtin_amdgcn_s_setprio(0);

  // Xs tap0+cond reads done; Zs may overwrite them. tap1 stays live.
  __syncthreads();

  // ---- gating (in-lane): z = tanh(f)*sigm(g) -> Zs(t, ch) in tap0 bytes ----
  {
    const int ch = wv * 16 + col;
    if (ch < 120) {
      const float bf_ = bias1[ch];
      const float bg_ = bias1[128 + ch];
#pragma unroll
      for (int tf = 0; tf < 4; ++tf) {
#pragma unroll
        for (int reg = 0; reg < 4; ++reg) {
          float f = acc[tf][0][reg] + bf_;
          float g = acc[tf][1][reg] + bg_;
          f = fminf(fmaxf(f, -15.f), 15.f);
          g = fminf(fmaxf(g, -15.f), 15.f);
          const float ef = __expf(2.0f * f);
          const float th = (ef - 1.0f) * __builtin_amdgcn_rcpf(ef + 1.0f);
          const float eg = __expf(-g);
          const float sg = __builtin_amdgcn_rcpf(1.0f + eg);
          const int t = tf * 16 + quad * 4 + reg;
          Xs[xswz(t, ch)] = f2bf(th * sg);
        }
      }
    }
  }
  if (tid < 64)   // zero k-pad: Zs ko 120..127 lives at k 240..247
    *(int4*)&Xs[xswz(tid, 240)] = make_int4(0, 0, 0, 0);
  __syncthreads();

  // ---- this tile's skips old-value prefetch (R5-proven slot) ----
  const size_t srow = ((size_t)bb * L_ + t0) * 240;
  int4 sk[4];
#pragma unroll
  for (int i = 0; i < 4; ++i) sk[i] = make_int4(0, 0, 0, 0);
  if (!first) {
#pragma unroll
    for (int i = 0; i < 4; ++i) {
      const int idx = tid + i * 512;
      if (idx < 1920) {
        const int row = idx / 30, j = idx - row * 30;
        sk[i] = *(const int4*)(skips + srow + row * 240 + j * 8);
      }
    }
  }

  // ---- GEMM2: A = Zs (ko<120 at k=ko, ko>=120 pad at k=ko+120) ----
  f32x4 acc2[4][3];
#pragma unroll
  for (int a = 0; a < 4; ++a)
#pragma unroll
    for (int b = 0; b < 3; ++b) acc2[a][b] = (f32x4)(0.f);
  __builtin_amdgcn_s_setprio(1);
#pragma unroll
  for (int ks = 0; ks < 4; ++ks) {
    const int ko = ks * 32 + kq;
    const int kz = (ko >= 120) ? (ko + 120) : ko;
    bf16x8 av[4];
#pragma unroll
    for (int tf = 0; tf < 4; ++tf)
      av[tf] = *(const bf16x8*)&Xs[xswz(tf * 16 + col, kz)];
#pragma unroll
    for (int st = 0; st < 3; ++st) {
      bf16x8 b = *(const bf16x8*)(W2 + ((wv * 3 + st) * 16 + col) * 128 + ks * 32 + kq);
#pragma unroll
      for (int tf = 0; tf < 4; ++tf)
        acc2[tf][st] = __builtin_amdgcn_mfma_f32_16x16x32_bf16(av[tf], b, acc2[tf][st], 0, 0, 0);
    }
  }
  __builtin_amdgcn_s_setprio(0);

  // ---- PREF: issue next-tile staging loads into regs (latency hides under
  //      phaseA/phaseB/RMW; consumed by caller's stage2 ds_writes) ----
  if (PREF) {
#pragma unroll
    for (int i = 0; i < 4; ++i) {
      const int idx = tid + i * 512;
      int4 v = make_int4(0, 0, 0, 0);
      if (idx < nr * 15) {
        const int rr = idx / 15, c8 = idx - rr * 15;
        int ts;
        if (d <= 64)      ts = t0n - d + rr;
        else              ts = (rr < 64) ? (t0n - 128 + rr) : (t0n + rr - 64);
        if (ts >= 0)
          v = *(const int4*)(res_in + ((size_t)(bb * L_ + ts) * 128 + c8 * 8));
      }
      rv[i] = v;
    }
#pragma unroll
    for (int i = 0; i < 2; ++i) {
      const int idx = tid + i * 512;
      if (idx < 640) {
        const int c = idx % 10, trw = idx / 10;
        cv[i] = *(const int4*)(condb + ((size_t)(bb * L_ + t0n + trw) * M_ + c * 8));
      }
    }
  }

  // ---- phase A: waves 5-7 write res_out using res_old from tap1 LDS ----
  if (wv >= 5) {
#pragma unroll
    for (int st = 0; st < 3; ++st) {
      const int tile = wv * 3 + st;
      if (tile < 23) {
        const int s = tile * 16 + col;
        const int r = s - 240;
        if (r < 120) {
          const float b2 = bias2[s];
#pragma unroll
          for (int tf = 0; tf < 4; ++tf) {
#pragma unroll
            for (int reg = 0; reg < 4; ++reg) {
              const int t = tf * 16 + quad * 4 + reg;
              const float old = bf2f((unsigned short)Xs[xswz(t, 120 + r)]);
              res_out[((size_t)(bb * L_ + t0 + t)) * 128 + r] =
                  f2bf(old + acc2[tf][st][reg] + b2);
            }
          }
        }
      }
    }
  }
  __syncthreads();   // A's tap1 reads + GEMM2's Zs reads done -> SG legal

  // ---- phase B: waves 0-4 stage skip tiles into SG (full Xs overlay) ----
  short* SG = Xs;
  if (wv < 5) {
#pragma unroll
    for (int st = 0; st < 3; ++st) {
      const int tile = wv * 3 + st;   // 0..14
      const int s = tile * 16 + col;
      const float b2 = bias2[s];
#pragma unroll
      for (int tf = 0; tf < 4; ++tf)
#pragma unroll
        for (int reg = 0; reg < 4; ++reg)
          SG[(tf * 16 + quad * 4 + reg) * SGP + s] = f2bf(acc2[tf][st][reg] + b2);
    }
  }
  __syncthreads();

  // ---- cooperative vectorized skips RMW: 64 rows x 240 shorts ----
#pragma unroll
  for (int it = 0; it < 4; ++it) {
    const int idx = tid + it * 512;
    if (idx < 1920) {
      const int row = idx / 30;
      const int j = idx - row * 30;
      unsigned short* gp = skips + srow + row * 240 + j * 8;
      int4 sv = *(const int4*)&SG[row * SGP + j * 8];
      const unsigned short* svp = (const unsigned short*)&sv;
      float vals[8];
#pragma unroll
      for (int e = 0; e < 8; ++e) vals[e] = bf2f(svp[e]);
      if (!first) {
        const unsigned short* ovp = (const unsigned short*)&sk[it];
#pragma unroll
        for (int e = 0; e < 8; ++e) vals[e] += bf2f(ovp[e]);
      }
      int4 res;
      unsigned short* rp = (unsigned short*)&res;
#pragma unroll
      for (int e = 0; e < 8; ++e) rp[e] = (unsigned short)f2bf(vals[e]);
      *(int4*)gp = res;
    }
  }
}

__global__ __launch_bounds__(512, 4) void block_mfma_kernel(
    const short* __restrict__ res_in, short* __restrict__ res_out,
    unsigned short* __restrict__ skips, const short* __restrict__ condb,
    const short* __restrict__ W1, const short* __restrict__ W2,
    const float* __restrict__ bias1, const float* __restrict__ bias2,
    const int d, const int first)
{
  __shared__ __align__(16) short Xs[64 * KP1];   // 40960 B; Zs/SG overlays

  const int tid = threadIdx.x;
  // XCD-chunked swizzle over 496 pair-WGs (496 = 8*62, bijective)
  const int w_id = blockIdx.x;
  const int nid  = (w_id & 7) * CPXB + (w_id >> 3);
  const int bb   = nid / NPAIR;
  const int tp   = nid - bb * NPAIR;
  const int t0a  = tp * 128;
  const int t0b  = t0a + 64;

  const int dd = (d <= 64) ? d : 64;
  const int nr = 64 + dd;

  const int lane = tid & 63;
  const int wv = tid >> 6;
  const int col = lane & 15;
  const int quad = lane >> 4;
  const int kq = quad * 8;

  // ---- stage tile1 direct: k [0,120)=res[t-d], [120,240)=res[t], [240,320)=cond
  for (int idx = tid; idx < nr * 15; idx += 512) {
    const int rr = idx / 15, c8 = idx - rr * 15;
    int ts;
    if (d <= 64)      ts = t0a - d + rr;
    else              ts = (rr < 64) ? (t0a - 128 + rr) : (t0a + rr - 64);
    int4 v = make_int4(0, 0, 0, 0);
    if (ts >= 0)
      v = *(const int4*)(res_in + ((size_t)(bb * L_ + ts) * 128 + c8 * 8));
    if (rr < 64)
      *(int4*)&Xs[xswz(rr, c8 * 8)] = v;                 // tap0
    const int r1 = rr - dd;
    if (r1 >= 0)
      *(int4*)&Xs[xswz(r1, 120 + c8 * 8)] = v;           // tap1
  }
  for (int idx = tid; idx < 640; idx += 512) {
    const int c = idx % 10, trw = idx / 10;
    const int4 v = *(const int4*)(condb + ((size_t)(bb * L_ + t0a + trw) * M_ + c * 8));
    *(int4*)&Xs[xswz(trw, 240 + c * 8)] = v;
  }
  __syncthreads();

  // ---- tile1 (prefetches tile2 staging into rv/cv during its back half) ----
  int4 rv[4], cv[2];
#pragma unroll
  for (int i = 0; i < 4; ++i) rv[i] = make_int4(0, 0, 0, 0);
#pragma unroll
  for (int i = 0; i < 2; ++i) cv[i] = make_int4(0, 0, 0, 0);

  tile_body<1>(Xs, tid, wv, col, quad, kq, bb, t0a, d, dd, nr, first,
               res_in, res_out, skips, condb, W1, W2, bias1, bias2,
               rv, cv, t0b);
  __syncthreads();   // RMW's SG reads done -> Xs free for tile2 staging

  // ---- stage tile2 from prefetched regs ----
#pragma unroll
  for (int i = 0; i < 4; ++i) {
    const int idx = tid + i * 512;
    if (idx < nr * 15) {
      const int rr = idx / 15, c8 = idx - rr * 15;
      if (rr < 64)
        *(int4*)&Xs[xswz(rr, c8 * 8)] = rv[i];           // tap0
      const int r1 = rr - dd;
      if (r1 >= 0)
        *(int4*)&Xs[xswz(r1, 120 + c8 * 8)] = rv[i];     // tap1
    }
  }
#pragma unroll
  for (int i = 0; i < 2; ++i) {
    const int idx = tid + i * 512;
    if (idx < 640) {
      const int c = idx % 10, trw = idx / 10;
      *(int4*)&Xs[xswz(trw, 240 + c * 8)] = cv[i];
    }
  }
  __syncthreads();

  // ---- tile2 (no further prefetch) ----
  tile_body<0>(Xs, tid, wv, col, quad, kq, bb, t0b, d, dd, nr, first,
               res_in, res_out, skips, condb, W1, W2, bias1, bias2,
               rv, cv, t0b);
}

// ---------------------------------------------------------------------------
// Head with 4-way q-split per wave. Hs overlays Ss (extra barrier) ->
// 33792 B LDS. Same XCD-chunked swizzle so skips reads hit the XCD-L2 slice
// the last block dispatch just wrote.
// ---------------------------------------------------------------------------
#define KPH 264

__global__ __launch_bounds__(256, 2) void head_mfma_kernel(
    const unsigned short* __restrict__ skips,
    const short* __restrict__ Wh1, const short* __restrict__ Wh2,
    const float* __restrict__ bh1, const float* __restrict__ bh2,
    float* __restrict__ out)
{
  __shared__ __align__(16) short Ss[64 * KPH];   // 33792 B; Hs overlays
  short* const Hs = Ss;

  const int tid = threadIdx.x;
  const int w_id = blockIdx.y * NTILE + blockIdx.x;
  const int nid  = (w_id & 7) * CPX + (w_id >> 3);
  const int bb   = nid / NTILE;
  const int t0   = (nid - bb * NTILE) * 64;

  for (int idx = tid; idx < 2048; idx += 256) {
    const int c = idx & 31, trw = idx >> 5;
    if (c < 30) {
      int4 v = *(const int4*)(skips + ((size_t)(bb * L_ + t0 + trw) * 240 + c * 8));
      int* vi = (int*)&v;
#pragma unroll
      for (int j = 0; j < 4; ++j) {
        unsigned x = (unsigned)vi[j];
        unsigned lo = x & 0xFFFFu; if (lo & 0x8000u) lo = 0;
        unsigned hi = x >> 16;     if (hi & 0x8000u) hi = 0;
        vi[j] = (int)(lo | (hi << 16));
      }
      *(int4*)&Ss[trw * KPH + c * 8] = v;
    } else {
      *(int4*)&Ss[trw * KPH + c * 8] = make_int4(0, 0, 0, 0);
    }
  }
  __syncthreads();

  const int lane = tid & 63;
  const int wv = tid >> 6;
  const int col = lane & 15;
  const int quad = lane >> 4;
  const int kq = quad * 8;

  f32x4 acc[4][4];
#pragma unroll
  for (int a = 0; a < 4; ++a)
#pragma unroll
    for (int b = 0; b < 4; ++b) acc[a][b] = (f32x4)(0.f);
#pragma unroll
  for (int ks = 0; ks < 8; ++ks) {
    bf16x8 av[4];
#pragma unroll
    for (int tf = 0; tf < 4; ++tf)
      av[tf] = *(const bf16x8*)&Ss[(tf * 16 + col) * KPH + ks * 32 + kq];
#pragma unroll
    for (int ct = 0; ct < 4; ++ct) {
      bf16x8 b = *(const bf16x8*)(Wh1 + ((wv * 4 + ct) * 16 + col) * 256 + ks * 32 + kq);
#pragma unroll
      for (int tf = 0; tf < 4; ++tf)
        acc[tf][ct] = __builtin_amdgcn_mfma_f32_16x16x32_bf16(av[tf], b, acc[tf][ct], 0, 0, 0);
    }
  }

  // all Ss reads are done; Hs may now overwrite the same storage
  __syncthreads();

#pragma unroll
  for (int ct = 0; ct < 4; ++ct) {
    const int q = (wv * 4 + ct) * 16 + col;
    const float b1 = bh1[q];
#pragma unroll
    for (int tf = 0; tf < 4; ++tf)
#pragma unroll
      for (int reg = 0; reg < 4; ++reg)
        Hs[(tf * 16 + quad * 4 + reg) * KPH + q] = f2bf(fmaxf(acc[tf][ct][reg] + b1, 0.0f));
  }
  __syncthreads();

  f32x4 acc2[4][4];
#pragma unroll
  for (int a = 0; a < 4; ++a)
#pragma unroll
    for (int b = 0; b < 4; ++b) acc2[a][b] = (f32x4)(0.f);
#pragma unroll
  for (int ks = 0; ks < 8; ++ks) {
    bf16x8 av[4];
#pragma unroll
    for (int tf = 0; tf < 4; ++tf)
      av[tf] = *(const bf16x8*)&Hs[(tf * 16 + col) * KPH + ks * 32 + kq];
#pragma unroll
    for (int ct = 0; ct < 4; ++ct) {
      bf16x8 b = *(const bf16x8*)(Wh2 + ((wv * 4 + ct) * 16 + col) * 256 + ks * 32 + kq);
#pragma unroll
      for (int tf = 0; tf < 4; ++tf)
        acc2[tf][ct] = __builtin_amdgcn_mfma_f32_16x16x32_bf16(av[tf], b, acc2[tf][ct], 0, 0, 0);
    }
  }
#pragma unroll
  for (int ct = 0; ct < 4; ++ct) {
    const int q = (wv * 4 + ct) * 16 + col;
    const float b2 = bh2[q];
#pragma unroll
    for (int tf = 0; tf < 4; ++tf) {
      const int tg0 = t0 + tf * 16 + quad * 4;
      float4 o = make_float4(acc2[tf][ct][0] + b2, acc2[tf][ct][1] + b2,
                             acc2[tf][ct][2] + b2, acc2[tf][ct][3] + b2);
      *(float4*)(out + ((size_t)(bb * Q_ + q)) * L_ + tg0) = o;
    }
  }
}

// ---------------------------------------------------------------------------
extern "C" void kernel_launch(void* const* d_in, const int* in_sizes, int n_in,
                              void* d_out, int out_size, void* d_ws, size_t ws_size,
                              hipStream_t stream) {
  const float* wav    = (const float*)d_in[0];
  const float* mel    = (const float*)d_in[1];
  const float* w_up   = (const float*)d_in[2];
  const float* b_up   = (const float*)d_in[3];
  const float* w_in   = (const float*)d_in[4];
  const float* b_in   = (const float*)d_in[5];
  const float* w_gate = (const float*)d_in[6];
  const float* b_gate = (const float*)d_in[7];
  const float* w_cond = (const float*)d_in[8];
  const float* b_cond = (const float*)d_in[9];
  const float* w_res  = (const float*)d_in[10];
  const float* b_res  = (const float*)d_in[11];
  const float* w_skip = (const float*)d_in[12];
  const float* b_skip = (const float*)d_in[13];
  const float* w_h1   = (const float*)d_in[14];
  const float* b_h1   = (const float*)d_in[15];
  const float* w_h2   = (const float*)d_in[16];
  const float* b_h2   = (const float*)d_in[17];
  float* out = (float*)d_out;

  char* w = (char*)d_ws;
  short* condb   = (short*)w;                 w += (size_t)B_ * L_ * M_ * 2;
  short* res0    = (short*)w;                 w += (size_t)B_ * L_ * 128 * 2;
  short* res1    = (short*)w;                 w += (size_t)B_ * L_ * 128 * 2;
  unsigned short* skips = (unsigned short*)w; w += (size_t)B_ * L_ * 240 * 2;
  short* W1p     = (short*)w;                 w += (size_t)16 * 256 * 320 * 2;
  short* W2p     = (short*)w;                 w += (size_t)16 * 384 * 128 * 2;
  short* Wh1p    = (short*)w;                 w += (size_t)256 * 256 * 2;
  short* Wh2p    = (short*)w;                 w += (size_t)256 * 256 * 2;
  float* bias1p  = (float*)w;                 w += (size_t)16 * 256 * 4;
  float* bias2p  = (float*)w;                 w += (size_t)16 * 384 * 4;
  short* melT    = (short*)w;                 w += (size_t)B_ * TMEL * M_ * 2;
  // Wup (13.1 MB) overlays skips: consumed before first block kernel.
  short* Wup = (short*)skips;

  prepack_w1_kernel<<<(16 * 256 * 320) / 256, 256, 0, stream>>>(w_gate, w_cond, W1p);
  prepack_w2_kernel<<<(16 * 384 * 128) / 256, 256, 0, stream>>>(w_skip, w_res, W2p);
  prepack_rest_kernel<<<141312 / 256, 256, 0, stream>>>(
      w_h1, w_h2, b_gate, b_cond, b_skip, b_res, Wh1p, Wh2p, bias1p, bias2p);
  prep_melT_kernel<<<(B_ * TMEL * M_ + 255) / 256, 256, 0, stream>>>(mel, melT);
  prep_wup_kernel<<<80 * 4 * 4, 256, 0, stream>>>(w_up, Wup);

  dim3 ugrid(256, 4);
  upsample_mfma_kernel<<<ugrid, 256, 0, stream>>>(melT, Wup, b_up, condb);
  in_conv_kernel<<<((size_t)B_ * L_ * 128) / 256, 256, 0, stream>>>(wav, w_in, b_in, res0);

  for (int i = 0; i < NB_; ++i) {
    const int d = 1 << (i & 7);
    const short* rin  = (i & 1) ? res1 : res0;
    short*       rout = (i & 1) ? res0 : res1;
    block_mfma_kernel<<<NWGB, 512, 0, stream>>>(
        rin, rout, skips, condb,
        W1p + (size_t)i * 256 * 320, W2p + (size_t)i * 384 * 128,
        bias1p + i * 256, bias2p + i * 384,
        d, (i == 0) ? 1 : 0);
  }

  dim3 bgrid(NTILE, B_);
  head_mfma_kernel<<<bgrid, 256, 0, stream>>>(skips, Wh1p, Wh2p, b_h1, b_h2, out);
}

// Round 7
// 1016.932 us; speedup vs baseline: 1.2793x; 1.2793x over previous
//
#include <hip/hip_runtime.h>
#include <math.h>

#define B_   4
#define M_   80
#define TMEL 63
#define R_   120
#define S_   240
#define Q_   256
#define NB_  16
#define L_   15872

typedef float  f32x4  __attribute__((ext_vector_type(4)));
typedef short  bf16x8 __attribute__((ext_vector_type(8)));
typedef short  short4_t __attribute__((ext_vector_type(4)));

__device__ __forceinline__ short f2bf(float x) {
  unsigned u = __builtin_bit_cast(unsigned, x);
  u += 0x7fffu + ((u >> 16) & 1u);
  return (short)(u >> 16);
}
__device__ __forceinline__ float bf2f(unsigned short s) {
  unsigned u = ((unsigned)s) << 16;
  return __builtin_bit_cast(float, u);
}

// ---------------------------------------------------------------------------
// melT[b][i][m] bf16  <-  mel[b][m][i] f32
// ---------------------------------------------------------------------------
__global__ __launch_bounds__(256) void prep_melT_kernel(
    const float* __restrict__ mel, short* __restrict__ melT)
{
  const int idx = blockIdx.x * 256 + threadIdx.x;
  if (idx >= B_ * TMEL * M_) return;
  const int m = idx % M_;
  const int i = (idx / M_) % TMEL;
  const int b = idx / (M_ * TMEL);
  melT[idx] = f2bf(mel[b * (M_ * TMEL) + m * TMEL + i]);
}

// ---------------------------------------------------------------------------
// Wup[phi][c][j*80+m] bf16
// ---------------------------------------------------------------------------
__global__ __launch_bounds__(256) void prep_wup_kernel(
    const float* __restrict__ w_up, short* __restrict__ Wup)
{
  __shared__ float T[M_][65];
  const int c  = blockIdx.x >> 4;
  const int j  = (blockIdx.x >> 2) & 3;
  const int fb = blockIdx.x & 3;
  for (int idx = threadIdx.x; idx < M_ * 64; idx += 256) {
    const int pl = idx & 63, m = idx >> 6;
    const int phi = fb * 64 + pl;
    const int dmin = (phi < 112) ? -1 : -2;
    const int dmax = (phi < 144) ? 1 : 0;
    const int delta = dmin + j;
    float v = 0.0f;
    if (delta <= dmax)
      v = w_up[m * (M_ * 800) + c * 800 + (400 + phi + 256 * delta)];
    T[m][pl] = v;
  }
  __syncthreads();
  for (int idx = threadIdx.x; idx < 64 * M_; idx += 256) {
    const int m = idx % M_, pl = idx / M_;
    const int phi = fb * 64 + pl;
    Wup[((size_t)phi * M_ + c) * 320 + j * 80 + m] = f2bf(T[m][pl]);
  }
}

// ---------------------------------------------------------------------------
// Upsample as per-phase MFMA GEMM -> condb[b][t][80] bf16
// ---------------------------------------------------------------------------
#define KPU 328

__global__ __launch_bounds__(256, 2) void upsample_mfma_kernel(
    const short* __restrict__ melT, const short* __restrict__ Wup,
    const float* __restrict__ b_up, short* __restrict__ condb)
{
  __shared__ __align__(16) short Xu[64 * KPU];
  const int tid = threadIdx.x;
  const int phi = blockIdx.x;
  const int r0 = blockIdx.y * 64;
  const int dmin = (phi < 112) ? -1 : -2;

  for (int idx = tid; idx < 2560; idx += 256) {
    const int v = idx % 10;
    const int j = (idx / 10) & 3;
    const int rl = idx / 40;
    const int rho = r0 + rl;
    const int b = rho / 62;
    const int n = rho - b * 62;
    const int i = n - (dmin + j);
    int4 val = make_int4(0, 0, 0, 0);
    if (b < B_ && i >= 0 && i < TMEL)
      val = *(const int4*)&melT[((size_t)b * TMEL + i) * M_ + v * 8];
    *(int4*)&Xu[rl * KPU + j * 80 + v * 8] = val;
  }
  __syncthreads();

  const int lane = tid & 63;
  const int wv = tid >> 6;
  const int col = lane & 15;
  const int quad = lane >> 4;
  const int kq = quad * 8;

  f32x4 acc[5];
#pragma unroll
  for (int i = 0; i < 5; ++i) acc[i] = (f32x4)(0.f);
#pragma unroll
  for (int ks = 0; ks < 10; ++ks) {
    bf16x8 a = *(const bf16x8*)&Xu[(wv * 16 + col) * KPU + ks * 32 + kq];
#pragma unroll
    for (int ct = 0; ct < 5; ++ct) {
      bf16x8 b = *(const bf16x8*)(Wup + ((size_t)phi * M_ + ct * 16 + col) * 320 + ks * 32 + kq);
      acc[ct] = __builtin_amdgcn_mfma_f32_16x16x32_bf16(a, b, acc[ct], 0, 0, 0);
    }
  }
#pragma unroll
  for (int ct = 0; ct < 5; ++ct) {
    const int c = ct * 16 + col;
    const float bc = b_up[c];
#pragma unroll
    for (int reg = 0; reg < 4; ++reg) {
      const int rho = r0 + wv * 16 + quad * 4 + reg;
      if (rho < 248) {
        const int b = rho / 62;
        const int n = rho - b * 62;
        const int t = phi + (n << 8);
        condb[((size_t)b * L_ + t) * M_ + c] = f2bf(acc[ct][reg] + bc);
      }
    }
  }
}

// res0[b][t][128] bf16
__global__ __launch_bounds__(256) void in_conv_kernel(
    const float* __restrict__ wav, const float* __restrict__ w_in,
    const float* __restrict__ b_in, short* __restrict__ res)
{
  const int idx = blockIdx.x * 256 + threadIdx.x;
  const int r = idx & 127;
  const int rem = idx >> 7;
  const int t = rem % L_;
  const int b = rem / L_;
  res[idx] = (r < R_) ? f2bf(w_in[r] * wav[b * L_ + t] + b_in[r]) : (short)0;
}

// ---------------------------------------------------------------------------
// Weight prepacks. W1p: f-channels cp 0..119 (tiles 0-7), g cp 128..247
// (tiles 8-15) -> in-lane gating. W2p[i][384][128]: sp<240 = Wsk rows
// (reused directly by head z-mode), sp 240..359 = Wres rows (tiles 15..22).
// ---------------------------------------------------------------------------
__global__ __launch_bounds__(256) void prepack_w1_kernel(
    const float* __restrict__ wg, const float* __restrict__ wc,
    short* __restrict__ W1p)
{
  const int idx = blockIdx.x * 256 + threadIdx.x;   // 16*256*320
  const int k = idx % 320;
  const int cp = (idx / 320) % 256;
  const int i = idx / (320 * 256);
  int corig = -1;
  if (cp < 128) { if (cp < 120) corig = cp; }
  else          { const int c = cp - 128; if (c < 120) corig = 120 + c; }
  float val = 0.0f;
  if (corig >= 0) {
    if (k < 120)      val = wg[((size_t)(i * 240 + corig) * 120 + k) * 2 + 0];
    else if (k < 240) val = wg[((size_t)(i * 240 + corig) * 120 + (k - 120)) * 2 + 1];
    else              val = wc[(size_t)(i * 240 + corig) * 80 + (k - 240)];
  }
  W1p[idx] = f2bf(val);
}

__global__ __launch_bounds__(256) void prepack_w2_kernel(
    const float* __restrict__ wsk, const float* __restrict__ wr,
    short* __restrict__ W2p)
{
  const int idx = blockIdx.x * 256 + threadIdx.x;   // 16*384*128
  const int k = idx % 128;
  const int sp = (idx / 128) % 384;
  const int i = idx / (128 * 384);
  float val = 0.0f;
  if (k < 120) {
    if (sp < 240)      val = wsk[(size_t)(i * 240 + sp) * 120 + k];
    else if (sp < 360) val = wr[(size_t)(i * 120 + (sp - 240)) * 120 + k];
  }
  W2p[idx] = f2bf(val);
}

__global__ __launch_bounds__(256) void prepack_rest_kernel(
    const float* __restrict__ wh1, const float* __restrict__ wh2,
    const float* __restrict__ bg, const float* __restrict__ bc,
    const float* __restrict__ bs, const float* __restrict__ br,
    short* __restrict__ Wh1p, short* __restrict__ Wh2p,
    float* __restrict__ bias1p, float* __restrict__ bias2p)
{
  const int idx = blockIdx.x * 256 + threadIdx.x;   // 141312
  if (idx < 65536) {
    const int q = idx >> 8, k = idx & 255;
    Wh1p[idx] = f2bf(k < 240 ? wh1[q * 240 + k] : 0.0f);
  } else if (idx < 131072) {
    Wh2p[idx - 65536] = f2bf(wh2[idx - 65536]);
  } else if (idx < 135168) {
    const int j = idx - 131072;
    const int i = j >> 8, cp = j & 255;
    float v = 0.0f;
    if (cp < 128) { if (cp < 120) v = bg[i * 240 + cp] + bc[i * 240 + cp]; }
    else { const int c = cp - 128; if (c < 120) v = bg[i * 240 + 120 + c] + bc[i * 240 + 120 + c]; }
    bias1p[j] = v;
  } else if (idx < 141312) {
    const int j = idx - 135168;
    const int i = j / 384, sp = j % 384;
    float v = 0.0f;
    if (sp < 240)      v = bs[i * 240 + sp];
    else if (sp < 360) v = br[i * 120 + (sp - 240)];
    bias2p[j] = v;
  }
}

// skipbias[s] = sum_i bs[i][s]  (z-path head adds it once)
__global__ __launch_bounds__(256) void sum_bs_kernel(
    const float* __restrict__ bs, float* __restrict__ skipbias)
{
  const int s = blockIdx.x * 256 + threadIdx.x;
  if (s < 240) {
    float v = 0.0f;
#pragma unroll
    for (int i = 0; i < NB_; ++i) v += bs[i * 240 + s];
    skipbias[s] = v;
  }
}

#define KP1 320
#define SGP 248
#define NTILE (L_ / 64)          // 248
#define NWG   (NTILE * B_)       // 992 -> bijective chunked swz (992%8==0)
#define CPX   (NWG / 8)          // 124
#define ZSTR  ((size_t)B_ * L_ * 128)

__device__ __forceinline__ int xswz(int row, int k) {
  return row * KP1 + (k ^ ((row & 7) << 3));
}

// ---------------------------------------------------------------------------
// Z-PATH residual block. R7: skips RMW deleted — gated z stored to zb
// (bf16 [b][t][128], pad cols zeroed); GEMM2 computes ONLY res tiles
// (sp 240..367 of W2p, 16 MFMA/wave vs 48). Chain: stage -> G1 -> gate ->
// {G2 + z-store + res-store}. 3 barriers (R5 had 5), no end-of-WG RMW.
// R6 lesson (reverted): pairing tiles halved grid to 1.9 WG/CU and
// address-taken prefetch arrays went to scratch (WRITE +67MB) — keep
// 992 WGs, 1 tile/WG, scalar regs only.
// ---------------------------------------------------------------------------
__global__ __launch_bounds__(512, 4) void block_mfma_z_kernel(
    const short* __restrict__ res_in, short* __restrict__ res_out,
    short* __restrict__ zb, const short* __restrict__ condb,
    const short* __restrict__ W1, const short* __restrict__ W2,
    const float* __restrict__ bias1, const float* __restrict__ bias2,
    const int d)
{
  __shared__ __align__(16) short Xs[64 * KP1];   // 40960 B; Zs overlays tap0

  const int tid = threadIdx.x;
  const int w_id = blockIdx.y * NTILE + blockIdx.x;
  const int nid  = (w_id & 7) * CPX + (w_id >> 3);
  const int bb   = nid / NTILE;
  const int t0   = (nid - bb * NTILE) * 64;

  // ---- stage X (merged taps): k [0,120)=res[t-d], [120,240)=res[t], [240,320)=cond
  {
    const int dd = (d <= 64) ? d : 64;
    const int nr = 64 + dd;
    for (int idx = tid; idx < nr * 15; idx += 512) {
      const int rr = idx / 15, c8 = idx - rr * 15;
      int ts;
      if (d <= 64)      ts = t0 - d + rr;
      else              ts = (rr < 64) ? (t0 - 128 + rr) : (t0 + rr - 64);
      int4 v = make_int4(0, 0, 0, 0);
      if (ts >= 0)
        v = *(const int4*)(res_in + ((size_t)(bb * L_ + ts) * 128 + c8 * 8));
      if (rr < 64)
        *(int4*)&Xs[xswz(rr, c8 * 8)] = v;                 // tap0
      const int r1 = rr - dd;
      if (r1 >= 0)
        *(int4*)&Xs[xswz(r1, 120 + c8 * 8)] = v;           // tap1
    }
  }
  for (int idx = tid; idx < 640; idx += 512) {
    const int c = idx % 10, trw = idx / 10;
    const int4 v = *(const int4*)(condb + ((size_t)(bb * L_ + t0 + trw) * M_ + c * 8));
    *(int4*)&Xs[xswz(trw, 240 + c * 8)] = v;
  }
  __syncthreads();

  const int lane = tid & 63;
  const int wv = tid >> 6;
  const int col = lane & 15;
  const int quad = lane >> 4;
  const int kq = quad * 8;

  // ---- GEMM1: ct=0 -> f-tile wv, ct=1 -> g-tile 8+wv ----
  f32x4 acc[4][2];
#pragma unroll
  for (int a = 0; a < 4; ++a)
#pragma unroll
    for (int b = 0; b < 2; ++b) acc[a][b] = (f32x4)(0.f);
  __builtin_amdgcn_s_setprio(1);
#pragma unroll
  for (int ks = 0; ks < 10; ++ks) {
    bf16x8 av[4];
#pragma unroll
    for (int tf = 0; tf < 4; ++tf)
      av[tf] = *(const bf16x8*)&Xs[xswz(tf * 16 + col, ks * 32 + kq)];
#pragma unroll
    for (int ct = 0; ct < 2; ++ct) {
      const int cpt = ((ct == 0) ? wv : (wv + 8)) * 16 + col;
      bf16x8 b = *(const bf16x8*)(W1 + cpt * 320 + ks * 32 + kq);
#pragma unroll
      for (int tf = 0; tf < 4; ++tf)
        acc[tf][ct] = __builtin_amdgcn_mfma_f32_16x16x32_bf16(av[tf], b, acc[tf][ct], 0, 0, 0);
    }
  }
  __builtin_amdgcn_s_setprio(0);
  __syncthreads();   // Xs tap0+cond reads done; Zs may overwrite. tap1 live.

  // ---- gating (in-lane): z -> Zs(t, ch) in tap0 bytes ----
  {
    const int ch = wv * 16 + col;
    if (ch < 120) {
      const float bf_ = bias1[ch];
      const float bg_ = bias1[128 + ch];
#pragma unroll
      for (int tf = 0; tf < 4; ++tf) {
#pragma unroll
        for (int reg = 0; reg < 4; ++reg) {
          float f = acc[tf][0][reg] + bf_;
          float g = acc[tf][1][reg] + bg_;
          f = fminf(fmaxf(f, -15.f), 15.f);
          g = fminf(fmaxf(g, -15.f), 15.f);
          const float ef = __expf(2.0f * f);
          const float th = (ef - 1.0f) * __builtin_amdgcn_rcpf(ef + 1.0f);
          const float eg = __expf(-g);
          const float sg = __builtin_amdgcn_rcpf(1.0f + eg);
          const int t = tf * 16 + quad * 4 + reg;
          Xs[xswz(t, ch)] = f2bf(th * sg);
        }
      }
    }
  }
  if (tid < 64)   // zero z pad (ko 120..127 lives at k 240..247)
    *(int4*)&Xs[xswz(tid, 240)] = make_int4(0, 0, 0, 0);
  __syncthreads();

  // ---- GEMM2 (res projection only): tile 15+wv of W2p ----
  const int sp = (15 + wv) * 16 + col;     // 240..367
  f32x4 acc2[4];
#pragma unroll
  for (int a = 0; a < 4; ++a) acc2[a] = (f32x4)(0.f);
  __builtin_amdgcn_s_setprio(1);
#pragma unroll
  for (int ks = 0; ks < 4; ++ks) {
    const int ko = ks * 32 + kq;
    const int kz = (ko >= 120) ? (ko + 120) : ko;
    bf16x8 b = *(const bf16x8*)(W2 + sp * 128 + ks * 32 + kq);
#pragma unroll
    for (int tf = 0; tf < 4; ++tf) {
      bf16x8 av = *(const bf16x8*)&Xs[xswz(tf * 16 + col, kz)];
      acc2[tf] = __builtin_amdgcn_mfma_f32_16x16x32_bf16(av, b, acc2[tf], 0, 0, 0);
    }
  }
  __builtin_amdgcn_s_setprio(0);

  // ---- z store: 64 rows x 16 int4 (j=15 -> zeroed pad) ----
  {
    const size_t zrow = ((size_t)(bb * L_ + t0)) * 128;
#pragma unroll
    for (int it = 0; it < 2; ++it) {
      const int idx = tid + it * 512;
      const int row = idx >> 4, j = idx & 15;
      const int4 v = *(const int4*)&Xs[xswz(row, (j < 15) ? j * 8 : 240)];
      *(int4*)&zb[zrow + (size_t)row * 128 + j * 8] = v;
    }
  }

  // ---- res store: r = wv*16+col, res_old from tap1 LDS ----
  {
    const int r = wv * 16 + col;
    if (r < 120) {
      const float b2 = bias2[sp];
#pragma unroll
      for (int tf = 0; tf < 4; ++tf) {
#pragma unroll
        for (int reg = 0; reg < 4; ++reg) {
          const int t = tf * 16 + quad * 4 + reg;
          const float old = bf2f((unsigned short)Xs[xswz(t, 120 + r)]);
          res_out[((size_t)(bb * L_ + t0 + t)) * 128 + r] =
              f2bf(old + acc2[tf][reg] + b2);
        }
      }
    }
  }
}

// ---------------------------------------------------------------------------
// Z-PATH head: skips = sum_i Wsk_i z_i (16 K=128 GEMMs, f32 accum, weights
// straight from W2p sp<240) + skipbias, then relu -> h1 -> relu -> h2.
// z tiles reg-double-buffered (scalar int4 vars — no arrays, R6 lesson).
// LDS: one 64*KPH buffer; z-stage uses [64][136] prefix, then relu'd skips
// occupy [64][KPH], then Hs overlays (R5 pattern).
// ---------------------------------------------------------------------------
#define KPH 264

__global__ __launch_bounds__(256, 2) void head_mfma_z_kernel(
    const short* __restrict__ zb, const short* __restrict__ W2,
    const short* __restrict__ Wh1, const short* __restrict__ Wh2,
    const float* __restrict__ skipbias, const float* __restrict__ bh1,
    const float* __restrict__ bh2, float* __restrict__ out)
{
  __shared__ __align__(16) short Sh[64 * KPH];   // 33792 B

  const int tid = threadIdx.x;
  const int w_id = blockIdx.y * NTILE + blockIdx.x;
  const int nid  = (w_id & 7) * CPX + (w_id >> 3);
  const int bb   = nid / NTILE;
  const int t0   = (nid - bb * NTILE) * 64;

  const int lane = tid & 63;
  const int wv = tid >> 6;
  const int col = lane & 15;
  const int quad = lane >> 4;
  const int kq = quad * 8;

  const int r0 = tid >> 4, j0 = tid & 15;
  const size_t gbase = ((size_t)(bb * L_ + t0)) * 128 + j0 * 8;

  // preload layer 0 z tile (4 int4/thread = 64 rows x 16 int4)
  int4 zv0 = *(const int4*)&zb[gbase + (size_t)(r0     ) * 128];
  int4 zv1 = *(const int4*)&zb[gbase + (size_t)(r0 + 16) * 128];
  int4 zv2 = *(const int4*)&zb[gbase + (size_t)(r0 + 32) * 128];
  int4 zv3 = *(const int4*)&zb[gbase + (size_t)(r0 + 48) * 128];

  f32x4 acc[4][4];
#pragma unroll
  for (int a = 0; a < 4; ++a)
#pragma unroll
    for (int b = 0; b < 4; ++b) acc[a][b] = (f32x4)(0.f);

  for (int i = 0; i < NB_; ++i) {
    *(int4*)&Sh[(r0     ) * 136 + j0 * 8] = zv0;
    *(int4*)&Sh[(r0 + 16) * 136 + j0 * 8] = zv1;
    *(int4*)&Sh[(r0 + 32) * 136 + j0 * 8] = zv2;
    *(int4*)&Sh[(r0 + 48) * 136 + j0 * 8] = zv3;
    __syncthreads();
    if (i < NB_ - 1) {   // prefetch next layer under the GEMM
      const short* zn = zb + (size_t)(i + 1) * ZSTR;
      zv0 = *(const int4*)&zn[gbase + (size_t)(r0     ) * 128];
      zv1 = *(const int4*)&zn[gbase + (size_t)(r0 + 16) * 128];
      zv2 = *(const int4*)&zn[gbase + (size_t)(r0 + 32) * 128];
      zv3 = *(const int4*)&zn[gbase + (size_t)(r0 + 48) * 128];
    }
    const short* Wl = W2 + (size_t)i * 384 * 128;
    __builtin_amdgcn_s_setprio(1);
#pragma unroll
    for (int ks = 0; ks < 4; ++ks) {
      bf16x8 av[4];
#pragma unroll
      for (int tf = 0; tf < 4; ++tf)
        av[tf] = *(const bf16x8*)&Sh[(tf * 16 + col) * 136 + ks * 32 + kq];
#pragma unroll
      for (int ct = 0; ct < 4; ++ct) {
        const int tile = wv * 4 + ct;
        if (tile < 15) {
          bf16x8 b = *(const bf16x8*)(Wl + (tile * 16 + col) * 128 + ks * 32 + kq);
#pragma unroll
          for (int tf = 0; tf < 4; ++tf)
            acc[tf][ct] = __builtin_amdgcn_mfma_f32_16x16x32_bf16(av[tf], b, acc[tf][ct], 0, 0, 0);
        }
      }
    }
    __builtin_amdgcn_s_setprio(0);
    __syncthreads();
  }

  // ---- relu(skips + skipbias) -> Sh[t][s] (KPH layout), zero s 240..255 ----
#pragma unroll
  for (int ct = 0; ct < 4; ++ct) {
    const int tile = wv * 4 + ct;
    if (tile < 15) {
      const int s = tile * 16 + col;
      const float sb = skipbias[s];
#pragma unroll
      for (int tf = 0; tf < 4; ++tf)
#pragma unroll
        for (int reg = 0; reg < 4; ++reg)
          Sh[(tf * 16 + quad * 4 + reg) * KPH + s] = f2bf(fmaxf(acc[tf][ct][reg] + sb, 0.0f));
    }
  }
  if (tid < 128) {
    const int row = tid >> 1, g = tid & 1;
    *(int4*)&Sh[row * KPH + 240 + g * 8] = make_int4(0, 0, 0, 0);
  }
  __syncthreads();

  // ---- h1 GEMM (K=256) ----
  f32x4 acc1[4][4];
#pragma unroll
  for (int a = 0; a < 4; ++a)
#pragma unroll
    for (int b = 0; b < 4; ++b) acc1[a][b] = (f32x4)(0.f);
#pragma unroll
  for (int ks = 0; ks < 8; ++ks) {
    bf16x8 av[4];
#pragma unroll
    for (int tf = 0; tf < 4; ++tf)
      av[tf] = *(const bf16x8*)&Sh[(tf * 16 + col) * KPH + ks * 32 + kq];
#pragma unroll
    for (int ct = 0; ct < 4; ++ct) {
      bf16x8 b = *(const bf16x8*)(Wh1 + ((wv * 4 + ct) * 16 + col) * 256 + ks * 32 + kq);
#pragma unroll
      for (int tf = 0; tf < 4; ++tf)
        acc1[tf][ct] = __builtin_amdgcn_mfma_f32_16x16x32_bf16(av[tf], b, acc1[tf][ct], 0, 0, 0);
    }
  }
  __syncthreads();   // Sh reads done; H overlays

#pragma unroll
  for (int ct = 0; ct < 4; ++ct) {
    const int q = (wv * 4 + ct) * 16 + col;
    const float b1 = bh1[q];
#pragma unroll
    for (int tf = 0; tf < 4; ++tf)
#pragma unroll
      for (int reg = 0; reg < 4; ++reg)
        Sh[(tf * 16 + quad * 4 + reg) * KPH + q] = f2bf(fmaxf(acc1[tf][ct][reg] + b1, 0.0f));
  }
  __syncthreads();

  // ---- h2 GEMM (K=256) -> out ----
  f32x4 acc2[4][4];
#pragma unroll
  for (int a = 0; a < 4; ++a)
#pragma unroll
    for (int b = 0; b < 4; ++b) acc2[a][b] = (f32x4)(0.f);
#pragma unroll
  for (int ks = 0; ks < 8; ++ks) {
    bf16x8 av[4];
#pragma unroll
    for (int tf = 0; tf < 4; ++tf)
      av[tf] = *(const bf16x8*)&Sh[(tf * 16 + col) * KPH + ks * 32 + kq];
#pragma unroll
    for (int ct = 0; ct < 4; ++ct) {
      bf16x8 b = *(const bf16x8*)(Wh2 + ((wv * 4 + ct) * 16 + col) * 256 + ks * 32 + kq);
#pragma unroll
      for (int tf = 0; tf < 4; ++tf)
        acc2[tf][ct] = __builtin_amdgcn_mfma_f32_16x16x32_bf16(av[tf], b, acc2[tf][ct], 0, 0, 0);
    }
  }
#pragma unroll
  for (int ct = 0; ct < 4; ++ct) {
    const int q = (wv * 4 + ct) * 16 + col;
    const float b2 = bh2[q];
#pragma unroll
    for (int tf = 0; tf < 4; ++tf) {
      const int tg0 = t0 + tf * 16 + quad * 4;
      float4 o = make_float4(acc2[tf][ct][0] + b2, acc2[tf][ct][1] + b2,
                             acc2[tf][ct][2] + b2, acc2[tf][ct][3] + b2);
      *(float4*)(out + ((size_t)(bb * Q_ + q)) * L_ + tg0) = o;
    }
  }
}

// ===========================================================================
// FALLBACK (R5, proven 1016us): skips global RMW path — used if ws_size is
// too small for the 16 z buffers.
// ===========================================================================
__global__ __launch_bounds__(512, 4) void block_mfma_kernel(
    const short* __restrict__ res_in, short* __restrict__ res_out,
    unsigned short* __restrict__ skips, const short* __restrict__ condb,
    const short* __restrict__ W1, const short* __restrict__ W2,
    const float* __restrict__ bias1, const float* __restrict__ bias2,
    const int d, const int first)
{
  __shared__ __align__(16) short Xs[64 * KP1];

  const int tid = threadIdx.x;
  const int w_id = blockIdx.y * NTILE + blockIdx.x;
  const int nid  = (w_id & 7) * CPX + (w_id >> 3);
  const int bb   = nid / NTILE;
  const int t0   = (nid - bb * NTILE) * 64;

  {
    const int dd = (d <= 64) ? d : 64;
    const int nr = 64 + dd;
    for (int idx = tid; idx < nr * 15; idx += 512) {
      const int rr = idx / 15, c8 = idx - rr * 15;
      int ts;
      if (d <= 64)      ts = t0 - d + rr;
      else              ts = (rr < 64) ? (t0 - 128 + rr) : (t0 + rr - 64);
      int4 v = make_int4(0, 0, 0, 0);
      if (ts >= 0)
        v = *(const int4*)(res_in + ((size_t)(bb * L_ + ts) * 128 + c8 * 8));
      if (rr < 64)
        *(int4*)&Xs[xswz(rr, c8 * 8)] = v;
      const int r1 = rr - dd;
      if (r1 >= 0)
        *(int4*)&Xs[xswz(r1, 120 + c8 * 8)] = v;
    }
  }
  for (int idx = tid; idx < 640; idx += 512) {
    const int c = idx % 10, trw = idx / 10;
    const int4 v = *(const int4*)(condb + ((size_t)(bb * L_ + t0 + trw) * M_ + c * 8));
    *(int4*)&Xs[xswz(trw, 240 + c * 8)] = v;
  }
  __syncthreads();

  const int lane = tid & 63;
  const int wv = tid >> 6;
  const int col = lane & 15;
  const int quad = lane >> 4;
  const int kq = quad * 8;

  f32x4 acc[4][2];
#pragma unroll
  for (int a = 0; a < 4; ++a)
#pragma unroll
    for (int b = 0; b < 2; ++b) acc[a][b] = (f32x4)(0.f);
  __builtin_amdgcn_s_setprio(1);
#pragma unroll
  for (int ks = 0; ks < 10; ++ks) {
    bf16x8 av[4];
#pragma unroll
    for (int tf = 0; tf < 4; ++tf)
      av[tf] = *(const bf16x8*)&Xs[xswz(tf * 16 + col, ks * 32 + kq)];
#pragma unroll
    for (int ct = 0; ct < 2; ++ct) {
      const int cpt = ((ct == 0) ? wv : (wv + 8)) * 16 + col;
      bf16x8 b = *(const bf16x8*)(W1 + cpt * 320 + ks * 32 + kq);
#pragma unroll
      for (int tf = 0; tf < 4; ++tf)
        acc[tf][ct] = __builtin_amdgcn_mfma_f32_16x16x32_bf16(av[tf], b, acc[tf][ct], 0, 0, 0);
    }
  }
  __builtin_amdgcn_s_setprio(0);
  __syncthreads();

  {
    const int ch = wv * 16 + col;
    if (ch < 120) {
      const float bf_ = bias1[ch];
      const float bg_ = bias1[128 + ch];
#pragma unroll
      for (int tf = 0; tf < 4; ++tf) {
#pragma unroll
        for (int reg = 0; reg < 4; ++reg) {
          float f = acc[tf][0][reg] + bf_;
          float g = acc[tf][1][reg] + bg_;
          f = fminf(fmaxf(f, -15.f), 15.f);
          g = fminf(fmaxf(g, -15.f), 15.f);
          const float ef = __expf(2.0f * f);
          const float th = (ef - 1.0f) * __builtin_amdgcn_rcpf(ef + 1.0f);
          const float eg = __expf(-g);
          const float sg = __builtin_amdgcn_rcpf(1.0f + eg);
          const int t = tf * 16 + quad * 4 + reg;
          Xs[xswz(t, ch)] = f2bf(th * sg);
        }
      }
    }
  }
  if (tid < 64)
    *(int4*)&Xs[xswz(tid, 240)] = make_int4(0, 0, 0, 0);
  __syncthreads();

  const size_t srow = ((size_t)bb * L_ + t0) * 240;
  int4 sk0 = make_int4(0,0,0,0), sk1 = sk0, sk2 = sk0, sk3 = sk0;
  if (!first) {
    { const int idx = tid;        const int row = idx / 30, j = idx - row * 30;
      sk0 = *(const int4*)(skips + srow + row * 240 + j * 8); }
    { const int idx = tid + 512;  const int row = idx / 30, j = idx - row * 30;
      sk1 = *(const int4*)(skips + srow + row * 240 + j * 8); }
    { const int idx = tid + 1024; const int row = idx / 30, j = idx - row * 30;
      sk2 = *(const int4*)(skips + srow + row * 240 + j * 8); }
    if (tid + 1536 < 1920) {
      const int idx = tid + 1536; const int row = idx / 30, j = idx - row * 30;
      sk3 = *(const int4*)(skips + srow + row * 240 + j * 8); }
  }

  f32x4 acc2[4][3];
#pragma unroll
  for (int a = 0; a < 4; ++a)
#pragma unroll
    for (int b = 0; b < 3; ++b) acc2[a][b] = (f32x4)(0.f);
  __builtin_amdgcn_s_setprio(1);
#pragma unroll
  for (int ks = 0; ks < 4; ++ks) {
    const int ko = ks * 32 + kq;
    const int kz = (ko >= 120) ? (ko + 120) : ko;
    bf16x8 av[4];
#pragma unroll
    for (int tf = 0; tf < 4; ++tf)
      av[tf] = *(const bf16x8*)&Xs[xswz(tf * 16 + col, kz)];
#pragma unroll
    for (int st = 0; st < 3; ++st) {
      bf16x8 b = *(const bf16x8*)(W2 + ((wv * 3 + st) * 16 + col) * 128 + ks * 32 + kq);
#pragma unroll
      for (int tf = 0; tf < 4; ++tf)
        acc2[tf][st] = __builtin_amdgcn_mfma_f32_16x16x32_bf16(av[tf], b, acc2[tf][st], 0, 0, 0);
    }
  }
  __builtin_amdgcn_s_setprio(0);

  if (wv >= 5) {
#pragma unroll
    for (int st = 0; st < 3; ++st) {
      const int tile = wv * 3 + st;
      if (tile < 23) {
        const int s = tile * 16 + col;
        const int r = s - 240;
        if (r < 120) {
          const float b2 = bias2[s];
#pragma unroll
          for (int tf = 0; tf < 4; ++tf) {
#pragma unroll
            for (int reg = 0; reg < 4; ++reg) {
              const int t = tf * 16 + quad * 4 + reg;
              const float old = bf2f((unsigned short)Xs[xswz(t, 120 + r)]);
              res_out[((size_t)(bb * L_ + t0 + t)) * 128 + r] =
                  f2bf(old + acc2[tf][st][reg] + b2);
            }
          }
        }
      }
    }
  }
  __syncthreads();

  short* SG = Xs;
  if (wv < 5) {
#pragma unroll
    for (int st = 0; st < 3; ++st) {
      const int tile = wv * 3 + st;
      const int s = tile * 16 + col;
      const float b2 = bias2[s];
#pragma unroll
      for (int tf = 0; tf < 4; ++tf)
#pragma unroll
        for (int reg = 0; reg < 4; ++reg)
          SG[(tf * 16 + quad * 4 + reg) * SGP + s] = f2bf(acc2[tf][st][reg] + b2);
    }
  }
  __syncthreads();

#pragma unroll
  for (int it = 0; it < 4; ++it) {
    const int idx = tid + it * 512;
    if (idx < 1920) {
      const int row = idx / 30;
      const int j = idx - row * 30;
      unsigned short* gp = skips + srow + row * 240 + j * 8;
      int4 sv = *(const int4*)&SG[row * SGP + j * 8];
      const unsigned short* svp = (const unsigned short*)&sv;
      float vals[8];
#pragma unroll
      for (int e = 0; e < 8; ++e) vals[e] = bf2f(svp[e]);
      if (!first) {
        const int4 ov = (it == 0) ? sk0 : (it == 1) ? sk1 : (it == 2) ? sk2 : sk3;
        const unsigned short* ovp = (const unsigned short*)&ov;
#pragma unroll
        for (int e = 0; e < 8; ++e) vals[e] += bf2f(ovp[e]);
      }
      int4 res;
      unsigned short* rp = (unsigned short*)&res;
#pragma unroll
      for (int e = 0; e < 8; ++e) rp[e] = (unsigned short)f2bf(vals[e]);
      *(int4*)gp = res;
    }
  }
}

__global__ __launch_bounds__(256, 2) void head_mfma_kernel(
    const unsigned short* __restrict__ skips,
    const short* __restrict__ Wh1, const short* __restrict__ Wh2,
    const float* __restrict__ bh1, const float* __restrict__ bh2,
    float* __restrict__ out)
{
  __shared__ __align__(16) short Ss[64 * KPH];
  short* const Hs = Ss;

  const int tid = threadIdx.x;
  const int w_id = blockIdx.y * NTILE + blockIdx.x;
  const int nid  = (w_id & 7) * CPX + (w_id >> 3);
  const int bb   = nid / NTILE;
  const int t0   = (nid - bb * NTILE) * 64;

  for (int idx = tid; idx < 2048; idx += 256) {
    const int c = idx & 31, trw = idx >> 5;
    if (c < 30) {
      int4 v = *(const int4*)(skips + ((size_t)(bb * L_ + t0 + trw) * 240 + c * 8));
      int* vi = (int*)&v;
#pragma unroll
      for (int j = 0; j < 4; ++j) {
        unsigned x = (unsigned)vi[j];
        unsigned lo = x & 0xFFFFu; if (lo & 0x8000u) lo = 0;
        unsigned hi = x >> 16;     if (hi & 0x8000u) hi = 0;
        vi[j] = (int)(lo | (hi << 16));
      }
      *(int4*)&Ss[trw * KPH + c * 8] = v;
    } else {
      *(int4*)&Ss[trw * KPH + c * 8] = make_int4(0, 0, 0, 0);
    }
  }
  __syncthreads();

  const int lane = tid & 63;
  const int wv = tid >> 6;
  const int col = lane & 15;
  const int quad = lane >> 4;
  const int kq = quad * 8;

  f32x4 acc[4][4];
#pragma unroll
  for (int a = 0; a < 4; ++a)
#pragma unroll
    for (int b = 0; b < 4; ++b) acc[a][b] = (f32x4)(0.f);
#pragma unroll
  for (int ks = 0; ks < 8; ++ks) {
    bf16x8 av[4];
#pragma unroll
    for (int tf = 0; tf < 4; ++tf)
      av[tf] = *(const bf16x8*)&Ss[(tf * 16 + col) * KPH + ks * 32 + kq];
#pragma unroll
    for (int ct = 0; ct < 4; ++ct) {
      bf16x8 b = *(const bf16x8*)(Wh1 + ((wv * 4 + ct) * 16 + col) * 256 + ks * 32 + kq);
#pragma unroll
      for (int tf = 0; tf < 4; ++tf)
        acc[tf][ct] = __builtin_amdgcn_mfma_f32_16x16x32_bf16(av[tf], b, acc[tf][ct], 0, 0, 0);
    }
  }
  __syncthreads();

#pragma unroll
  for (int ct = 0; ct < 4; ++ct) {
    const int q = (wv * 4 + ct) * 16 + col;
    const float b1 = bh1[q];
#pragma unroll
    for (int tf = 0; tf < 4; ++tf)
#pragma unroll
      for (int reg = 0; reg < 4; ++reg)
        Hs[(tf * 16 + quad * 4 + reg) * KPH + q] = f2bf(fmaxf(acc[tf][ct][reg] + b1, 0.0f));
  }
  __syncthreads();

  f32x4 acc2[4][4];
#pragma unroll
  for (int a = 0; a < 4; ++a)
#pragma unroll
    for (int b = 0; b < 4; ++b) acc2[a][b] = (f32x4)(0.f);
#pragma unroll
  for (int ks = 0; ks < 8; ++ks) {
    bf16x8 av[4];
#pragma unroll
    for (int tf = 0; tf < 4; ++tf)
      av[tf] = *(const bf16x8*)&Hs[(tf * 16 + col) * KPH + ks * 32 + kq];
#pragma unroll
    for (int ct = 0; ct < 4; ++ct) {
      bf16x8 b = *(const bf16x8*)(Wh2 + ((wv * 4 + ct) * 16 + col) * 256 + ks * 32 + kq);
#pragma unroll
      for (int tf = 0; tf < 4; ++tf)
        acc2[tf][ct] = __builtin_amdgcn_mfma_f32_16x16x32_bf16(av[tf], b, acc2[tf][ct], 0, 0, 0);
    }
  }
#pragma unroll
  for (int ct = 0; ct < 4; ++ct) {
    const int q = (wv * 4 + ct) * 16 + col;
    const float b2 = bh2[q];
#pragma unroll
    for (int tf = 0; tf < 4; ++tf) {
      const int tg0 = t0 + tf * 16 + quad * 4;
      float4 o = make_float4(acc2[tf][ct][0] + b2, acc2[tf][ct][1] + b2,
                             acc2[tf][ct][2] + b2, acc2[tf][ct][3] + b2);
      *(float4*)(out + ((size_t)(bb * Q_ + q)) * L_ + tg0) = o;
    }
  }
}

// ---------------------------------------------------------------------------
extern "C" void kernel_launch(void* const* d_in, const int* in_sizes, int n_in,
                              void* d_out, int out_size, void* d_ws, size_t ws_size,
                              hipStream_t stream) {
  const float* wav    = (const float*)d_in[0];
  const float* mel    = (const float*)d_in[1];
  const float* w_up   = (const float*)d_in[2];
  const float* b_up   = (const float*)d_in[3];
  const float* w_in   = (const float*)d_in[4];
  const float* b_in   = (const float*)d_in[5];
  const float* w_gate = (const float*)d_in[6];
  const float* b_gate = (const float*)d_in[7];
  const float* w_cond = (const float*)d_in[8];
  const float* b_cond = (const float*)d_in[9];
  const float* w_res  = (const float*)d_in[10];
  const float* b_res  = (const float*)d_in[11];
  const float* w_skip = (const float*)d_in[12];
  const float* b_skip = (const float*)d_in[13];
  const float* w_h1   = (const float*)d_in[14];
  const float* b_h1   = (const float*)d_in[15];
  const float* w_h2   = (const float*)d_in[16];
  const float* b_h2   = (const float*)d_in[17];
  float* out = (float*)d_out;

  const size_t SZ_condb = (size_t)B_ * L_ * M_ * 2;
  const size_t SZ_res   = (size_t)B_ * L_ * 128 * 2;
  const size_t SZ_zb    = ZSTR * 2;                 // one z layer (bf16)
  const size_t SZ_W1p   = (size_t)16 * 256 * 320 * 2;
  const size_t SZ_W2p   = (size_t)16 * 384 * 128 * 2;
  const size_t SZ_Wh    = (size_t)256 * 256 * 2;
  const size_t SZ_b1    = (size_t)16 * 256 * 4;
  const size_t SZ_b2    = (size_t)16 * 384 * 4;
  const size_t SZ_melT  = (size_t)B_ * TMEL * M_ * 2;
  const size_t NEED_Z = SZ_condb + 2 * SZ_res + 16 * SZ_zb + SZ_W1p + SZ_W2p
                      + 2 * SZ_Wh + SZ_b1 + SZ_b2 + 1024 + SZ_melT;

  if (ws_size >= NEED_Z) {
    // ---------------- z path ----------------
    char* w = (char*)d_ws;
    short* condb   = (short*)w;  w += SZ_condb;
    short* res0    = (short*)w;  w += SZ_res;
    short* res1    = (short*)w;  w += SZ_res;
    short* zb      = (short*)w;  w += 16 * SZ_zb;
    short* W1p     = (short*)w;  w += SZ_W1p;
    short* W2p     = (short*)w;  w += SZ_W2p;
    short* Wh1p    = (short*)w;  w += SZ_Wh;
    short* Wh2p    = (short*)w;  w += SZ_Wh;
    float* bias1p  = (float*)w;  w += SZ_b1;
    float* bias2p  = (float*)w;  w += SZ_b2;
    float* skipbias= (float*)w;  w += 1024;
    short* melT    = (short*)w;  w += SZ_melT;
    short* Wup = zb;   // 13.1 MB overlay; consumed before layer 0 writes zb[0]

    prepack_w1_kernel<<<(16 * 256 * 320) / 256, 256, 0, stream>>>(w_gate, w_cond, W1p);
    prepack_w2_kernel<<<(16 * 384 * 128) / 256, 256, 0, stream>>>(w_skip, w_res, W2p);
    prepack_rest_kernel<<<141312 / 256, 256, 0, stream>>>(
        w_h1, w_h2, b_gate, b_cond, b_skip, b_res, Wh1p, Wh2p, bias1p, bias2p);
    sum_bs_kernel<<<1, 256, 0, stream>>>(b_skip, skipbias);
    prep_melT_kernel<<<(B_ * TMEL * M_ + 255) / 256, 256, 0, stream>>>(mel, melT);
    prep_wup_kernel<<<80 * 4 * 4, 256, 0, stream>>>(w_up, Wup);

    dim3 ugrid(256, 4);
    upsample_mfma_kernel<<<ugrid, 256, 0, stream>>>(melT, Wup, b_up, condb);
    in_conv_kernel<<<((size_t)B_ * L_ * 128) / 256, 256, 0, stream>>>(wav, w_in, b_in, res0);

    dim3 bgrid(NTILE, B_);
    for (int i = 0; i < NB_; ++i) {
      const int d = 1 << (i & 7);
      const short* rin  = (i & 1) ? res1 : res0;
      short*       rout = (i & 1) ? res0 : res1;
      block_mfma_z_kernel<<<bgrid, 512, 0, stream>>>(
          rin, rout, zb + (size_t)i * ZSTR, condb,
          W1p + (size_t)i * 256 * 320, W2p + (size_t)i * 384 * 128,
          bias1p + i * 256, bias2p + i * 384, d);
    }
    head_mfma_z_kernel<<<bgrid, 256, 0, stream>>>(
        zb, W2p, Wh1p, Wh2p, skipbias, b_h1, b_h2, out);
  } else {
    // ---------------- fallback: R5 path ----------------
    char* w = (char*)d_ws;
    short* condb   = (short*)w;                 w += SZ_condb;
    short* res0    = (short*)w;                 w += SZ_res;
    short* res1    = (short*)w;                 w += SZ_res;
    unsigned short* skips = (unsigned short*)w; w += (size_t)B_ * L_ * 240 * 2;
    short* W1p     = (short*)w;                 w += SZ_W1p;
    short* W2p     = (short*)w;                 w += SZ_W2p;
    short* Wh1p    = (short*)w;                 w += SZ_Wh;
    short* Wh2p    = (short*)w;                 w += SZ_Wh;
    float* bias1p  = (float*)w;                 w += SZ_b1;
    float* bias2p  = (float*)w;                 w += SZ_b2;
    short* melT    = (short*)w;                 w += SZ_melT;
    short* Wup = (short*)skips;

    prepack_w1_kernel<<<(16 * 256 * 320) / 256, 256, 0, stream>>>(w_gate, w_cond, W1p);
    prepack_w2_kernel<<<(16 * 384 * 128) / 256, 256, 0, stream>>>(w_skip, w_res, W2p);
    prepack_rest_kernel<<<141312 / 256, 256, 0, stream>>>(
        w_h1, w_h2, b_gate, b_cond, b_skip, b_res, Wh1p, Wh2p, bias1p, bias2p);
    prep_melT_kernel<<<(B_ * TMEL * M_ + 255) / 256, 256, 0, stream>>>(mel, melT);
    prep_wup_kernel<<<80 * 4 * 4, 256, 0, stream>>>(w_up, Wup);

    dim3 ugrid(256, 4);
    upsample_mfma_kernel<<<ugrid, 256, 0, stream>>>(melT, Wup, b_up, condb);
    in_conv_kernel<<<((size_t)B_ * L_ * 128) / 256, 256, 0, stream>>>(wav, w_in, b_in, res0);

    dim3 bgrid(NTILE, B_);
    for (int i = 0; i < NB_; ++i) {
      const int d = 1 << (i & 7);
      const short* rin  = (i & 1) ? res1 : res0;
      short*       rout = (i & 1) ? res0 : res1;
      block_mfma_kernel<<<bgrid, 512, 0, stream>>>(
          rin, rout, skips, condb,
          W1p + (size_t)i * 256 * 320, W2p + (size_t)i * 384 * 128,
          bias1p + i * 256, bias2p + i * 384,
          d, (i == 0) ? 1 : 0);
    }
    head_mfma_kernel<<<bgrid, 256, 0, stream>>>(skips, Wh1p, Wh2p, b_h1, b_h2, out);
  }
}

// Round 8
// 994.323 us; speedup vs baseline: 1.3084x; 1.0227x over previous
//
#include <hip/hip_runtime.h>
#include <math.h>

#define B_   4
#define M_   80
#define TMEL 63
#define R_   120
#define S_   240
#define Q_   256
#define NB_  16
#define L_   15872

typedef float  f32x4  __attribute__((ext_vector_type(4)));
typedef short  bf16x8 __attribute__((ext_vector_type(8)));
typedef short  short4_t __attribute__((ext_vector_type(4)));

__device__ __forceinline__ short f2bf(float x) {
  unsigned u = __builtin_bit_cast(unsigned, x);
  u += 0x7fffu + ((u >> 16) & 1u);
  return (short)(u >> 16);
}
__device__ __forceinline__ float bf2f(unsigned short s) {
  unsigned u = ((unsigned)s) << 16;
  return __builtin_bit_cast(float, u);
}

// ---------------------------------------------------------------------------
// melT[b][i][m] bf16  <-  mel[b][m][i] f32
// ---------------------------------------------------------------------------
__global__ __launch_bounds__(256) void prep_melT_kernel(
    const float* __restrict__ mel, short* __restrict__ melT)
{
  const int idx = blockIdx.x * 256 + threadIdx.x;
  if (idx >= B_ * TMEL * M_) return;
  const int m = idx % M_;
  const int i = (idx / M_) % TMEL;
  const int b = idx / (M_ * TMEL);
  melT[idx] = f2bf(mel[b * (M_ * TMEL) + m * TMEL + i]);
}

// ---------------------------------------------------------------------------
// Wup[phi][c][j*80+m] bf16
// ---------------------------------------------------------------------------
__global__ __launch_bounds__(256) void prep_wup_kernel(
    const float* __restrict__ w_up, short* __restrict__ Wup)
{
  __shared__ float T[M_][65];
  const int c  = blockIdx.x >> 4;
  const int j  = (blockIdx.x >> 2) & 3;
  const int fb = blockIdx.x & 3;
  for (int idx = threadIdx.x; idx < M_ * 64; idx += 256) {
    const int pl = idx & 63, m = idx >> 6;
    const int phi = fb * 64 + pl;
    const int dmin = (phi < 112) ? -1 : -2;
    const int dmax = (phi < 144) ? 1 : 0;
    const int delta = dmin + j;
    float v = 0.0f;
    if (delta <= dmax)
      v = w_up[m * (M_ * 800) + c * 800 + (400 + phi + 256 * delta)];
    T[m][pl] = v;
  }
  __syncthreads();
  for (int idx = threadIdx.x; idx < 64 * M_; idx += 256) {
    const int m = idx % M_, pl = idx / M_;
    const int phi = fb * 64 + pl;
    Wup[((size_t)phi * M_ + c) * 320 + j * 80 + m] = f2bf(T[m][pl]);
  }
}

// ---------------------------------------------------------------------------
// Upsample as per-phase MFMA GEMM -> condb[b][t][80] bf16
// ---------------------------------------------------------------------------
#define KPU 328

__global__ __launch_bounds__(256, 2) void upsample_mfma_kernel(
    const short* __restrict__ melT, const short* __restrict__ Wup,
    const float* __restrict__ b_up, short* __restrict__ condb)
{
  __shared__ __align__(16) short Xu[64 * KPU];
  const int tid = threadIdx.x;
  const int phi = blockIdx.x;
  const int r0 = blockIdx.y * 64;
  const int dmin = (phi < 112) ? -1 : -2;

  for (int idx = tid; idx < 2560; idx += 256) {
    const int v = idx % 10;
    const int j = (idx / 10) & 3;
    const int rl = idx / 40;
    const int rho = r0 + rl;
    const int b = rho / 62;
    const int n = rho - b * 62;
    const int i = n - (dmin + j);
    int4 val = make_int4(0, 0, 0, 0);
    if (b < B_ && i >= 0 && i < TMEL)
      val = *(const int4*)&melT[((size_t)b * TMEL + i) * M_ + v * 8];
    *(int4*)&Xu[rl * KPU + j * 80 + v * 8] = val;
  }
  __syncthreads();

  const int lane = tid & 63;
  const int wv = tid >> 6;
  const int col = lane & 15;
  const int quad = lane >> 4;
  const int kq = quad * 8;

  f32x4 acc[5];
#pragma unroll
  for (int i = 0; i < 5; ++i) acc[i] = (f32x4)(0.f);
#pragma unroll
  for (int ks = 0; ks < 10; ++ks) {
    bf16x8 a = *(const bf16x8*)&Xu[(wv * 16 + col) * KPU + ks * 32 + kq];
#pragma unroll
    for (int ct = 0; ct < 5; ++ct) {
      bf16x8 b = *(const bf16x8*)(Wup + ((size_t)phi * M_ + ct * 16 + col) * 320 + ks * 32 + kq);
      acc[ct] = __builtin_amdgcn_mfma_f32_16x16x32_bf16(a, b, acc[ct], 0, 0, 0);
    }
  }
#pragma unroll
  for (int ct = 0; ct < 5; ++ct) {
    const int c = ct * 16 + col;
    const float bc = b_up[c];
#pragma unroll
    for (int reg = 0; reg < 4; ++reg) {
      const int rho = r0 + wv * 16 + quad * 4 + reg;
      if (rho < 248) {
        const int b = rho / 62;
        const int n = rho - b * 62;
        const int t = phi + (n << 8);
        condb[((size_t)b * L_ + t) * M_ + c] = f2bf(acc[ct][reg] + bc);
      }
    }
  }
}

// res0[b][t][128] bf16
__global__ __launch_bounds__(256) void in_conv_kernel(
    const float* __restrict__ wav, const float* __restrict__ w_in,
    const float* __restrict__ b_in, short* __restrict__ res)
{
  const int idx = blockIdx.x * 256 + threadIdx.x;
  const int r = idx & 127;
  const int rem = idx >> 7;
  const int t = rem % L_;
  const int b = rem / L_;
  res[idx] = (r < R_) ? f2bf(w_in[r] * wav[b * L_ + t] + b_in[r]) : (short)0;
}

// ---------------------------------------------------------------------------
// Weight prepacks. W1p: f-channels cp 0..119 (tiles 0-7), g cp 128..247
// (tiles 8-15) -> in-lane gating. W2p[i][384][128]: sp<240 = Wsk,
// sp 240..359 = Wres.
// ---------------------------------------------------------------------------
__global__ __launch_bounds__(256) void prepack_w1_kernel(
    const float* __restrict__ wg, const float* __restrict__ wc,
    short* __restrict__ W1p)
{
  const int idx = blockIdx.x * 256 + threadIdx.x;   // 16*256*320
  const int k = idx % 320;
  const int cp = (idx / 320) % 256;
  const int i = idx / (320 * 256);
  int corig = -1;
  if (cp < 128) { if (cp < 120) corig = cp; }
  else          { const int c = cp - 128; if (c < 120) corig = 120 + c; }
  float val = 0.0f;
  if (corig >= 0) {
    if (k < 120)      val = wg[((size_t)(i * 240 + corig) * 120 + k) * 2 + 0];
    else if (k < 240) val = wg[((size_t)(i * 240 + corig) * 120 + (k - 120)) * 2 + 1];
    else              val = wc[(size_t)(i * 240 + corig) * 80 + (k - 240)];
  }
  W1p[idx] = f2bf(val);
}

__global__ __launch_bounds__(256) void prepack_w2_kernel(
    const float* __restrict__ wsk, const float* __restrict__ wr,
    short* __restrict__ W2p)
{
  const int idx = blockIdx.x * 256 + threadIdx.x;   // 16*384*128
  const int k = idx % 128;
  const int sp = (idx / 128) % 384;
  const int i = idx / (128 * 384);
  float val = 0.0f;
  if (k < 120) {
    if (sp < 240)      val = wsk[(size_t)(i * 240 + sp) * 120 + k];
    else if (sp < 360) val = wr[(size_t)(i * 120 + (sp - 240)) * 120 + k];
  }
  W2p[idx] = f2bf(val);
}

__global__ __launch_bounds__(256) void prepack_rest_kernel(
    const float* __restrict__ wh1, const float* __restrict__ wh2,
    const float* __restrict__ bg, const float* __restrict__ bc,
    const float* __restrict__ bs, const float* __restrict__ br,
    short* __restrict__ Wh1p, short* __restrict__ Wh2p,
    float* __restrict__ bias1p, float* __restrict__ bias2p)
{
  const int idx = blockIdx.x * 256 + threadIdx.x;   // 141312
  if (idx < 65536) {
    const int q = idx >> 8, k = idx & 255;
    Wh1p[idx] = f2bf(k < 240 ? wh1[q * 240 + k] : 0.0f);
  } else if (idx < 131072) {
    Wh2p[idx - 65536] = f2bf(wh2[idx - 65536]);
  } else if (idx < 135168) {
    const int j = idx - 131072;
    const int i = j >> 8, cp = j & 255;
    float v = 0.0f;
    if (cp < 128) { if (cp < 120) v = bg[i * 240 + cp] + bc[i * 240 + cp]; }
    else { const int c = cp - 128; if (c < 120) v = bg[i * 240 + 120 + c] + bc[i * 240 + 120 + c]; }
    bias1p[j] = v;
  } else if (idx < 141312) {
    const int j = idx - 135168;
    const int i = j / 384, sp = j % 384;
    float v = 0.0f;
    if (sp < 240)      v = bs[i * 240 + sp];
    else if (sp < 360) v = br[i * 120 + (sp - 240)];
    bias2p[j] = v;
  }
}

#define KP1 320
#define SGP 248
#define SGP2 264
#define NTILE (L_ / 64)          // 248
#define NWG   (NTILE * B_)       // 992 -> bijective chunked swz (992%8==0)
#define CPX   (NWG / 8)          // 124

__device__ __forceinline__ int xswz(int row, int k) {
  return row * KP1 + (k ^ ((row & 7) << 3));
}

// ---------------------------------------------------------------------------
// Layers 0..14 (R5-proven, 54.5us/dispatch, 64 VGPR). Unchanged.
// ---------------------------------------------------------------------------
__global__ __launch_bounds__(512, 4) void block_mfma_kernel(
    const short* __restrict__ res_in, short* __restrict__ res_out,
    unsigned short* __restrict__ skips, const short* __restrict__ condb,
    const short* __restrict__ W1, const short* __restrict__ W2,
    const float* __restrict__ bias1, const float* __restrict__ bias2,
    const int d, const int first)
{
  __shared__ __align__(16) short Xs[64 * KP1];

  const int tid = threadIdx.x;
  const int w_id = blockIdx.y * NTILE + blockIdx.x;
  const int nid  = (w_id & 7) * CPX + (w_id >> 3);
  const int bb   = nid / NTILE;
  const int t0   = (nid - bb * NTILE) * 64;

  {
    const int dd = (d <= 64) ? d : 64;
    const int nr = 64 + dd;
    for (int idx = tid; idx < nr * 15; idx += 512) {
      const int rr = idx / 15, c8 = idx - rr * 15;
      int ts;
      if (d <= 64)      ts = t0 - d + rr;
      else              ts = (rr < 64) ? (t0 - 128 + rr) : (t0 + rr - 64);
      int4 v = make_int4(0, 0, 0, 0);
      if (ts >= 0)
        v = *(const int4*)(res_in + ((size_t)(bb * L_ + ts) * 128 + c8 * 8));
      if (rr < 64)
        *(int4*)&Xs[xswz(rr, c8 * 8)] = v;
      const int r1 = rr - dd;
      if (r1 >= 0)
        *(int4*)&Xs[xswz(r1, 120 + c8 * 8)] = v;
    }
  }
  for (int idx = tid; idx < 640; idx += 512) {
    const int c = idx % 10, trw = idx / 10;
    const int4 v = *(const int4*)(condb + ((size_t)(bb * L_ + t0 + trw) * M_ + c * 8));
    *(int4*)&Xs[xswz(trw, 240 + c * 8)] = v;
  }
  __syncthreads();

  const int lane = tid & 63;
  const int wv = tid >> 6;
  const int col = lane & 15;
  const int quad = lane >> 4;
  const int kq = quad * 8;

  f32x4 acc[4][2];
#pragma unroll
  for (int a = 0; a < 4; ++a)
#pragma unroll
    for (int b = 0; b < 2; ++b) acc[a][b] = (f32x4)(0.f);
  __builtin_amdgcn_s_setprio(1);
#pragma unroll
  for (int ks = 0; ks < 10; ++ks) {
    bf16x8 av[4];
#pragma unroll
    for (int tf = 0; tf < 4; ++tf)
      av[tf] = *(const bf16x8*)&Xs[xswz(tf * 16 + col, ks * 32 + kq)];
#pragma unroll
    for (int ct = 0; ct < 2; ++ct) {
      const int cpt = ((ct == 0) ? wv : (wv + 8)) * 16 + col;
      bf16x8 b = *(const bf16x8*)(W1 + cpt * 320 + ks * 32 + kq);
#pragma unroll
      for (int tf = 0; tf < 4; ++tf)
        acc[tf][ct] = __builtin_amdgcn_mfma_f32_16x16x32_bf16(av[tf], b, acc[tf][ct], 0, 0, 0);
    }
  }
  __builtin_amdgcn_s_setprio(0);
  __syncthreads();

  {
    const int ch = wv * 16 + col;
    if (ch < 120) {
      const float bf_ = bias1[ch];
      const float bg_ = bias1[128 + ch];
#pragma unroll
      for (int tf = 0; tf < 4; ++tf) {
#pragma unroll
        for (int reg = 0; reg < 4; ++reg) {
          float f = acc[tf][0][reg] + bf_;
          float g = acc[tf][1][reg] + bg_;
          f = fminf(fmaxf(f, -15.f), 15.f);
          g = fminf(fmaxf(g, -15.f), 15.f);
          const float ef = __expf(2.0f * f);
          const float th = (ef - 1.0f) * __builtin_amdgcn_rcpf(ef + 1.0f);
          const float eg = __expf(-g);
          const float sg = __builtin_amdgcn_rcpf(1.0f + eg);
          const int t = tf * 16 + quad * 4 + reg;
          Xs[xswz(t, ch)] = f2bf(th * sg);
        }
      }
    }
  }
  if (tid < 64)
    *(int4*)&Xs[xswz(tid, 240)] = make_int4(0, 0, 0, 0);
  __syncthreads();

  const size_t srow = ((size_t)bb * L_ + t0) * 240;
  int4 sk0 = make_int4(0,0,0,0), sk1 = sk0, sk2 = sk0, sk3 = sk0;
  if (!first) {
    { const int idx = tid;        const int row = idx / 30, j = idx - row * 30;
      sk0 = *(const int4*)(skips + srow + row * 240 + j * 8); }
    { const int idx = tid + 512;  const int row = idx / 30, j = idx - row * 30;
      sk1 = *(const int4*)(skips + srow + row * 240 + j * 8); }
    { const int idx = tid + 1024; const int row = idx / 30, j = idx - row * 30;
      sk2 = *(const int4*)(skips + srow + row * 240 + j * 8); }
    if (tid + 1536 < 1920) {
      const int idx = tid + 1536; const int row = idx / 30, j = idx - row * 30;
      sk3 = *(const int4*)(skips + srow + row * 240 + j * 8); }
  }

  f32x4 acc2[4][3];
#pragma unroll
  for (int a = 0; a < 4; ++a)
#pragma unroll
    for (int b = 0; b < 3; ++b) acc2[a][b] = (f32x4)(0.f);
  __builtin_amdgcn_s_setprio(1);
#pragma unroll
  for (int ks = 0; ks < 4; ++ks) {
    const int ko = ks * 32 + kq;
    const int kz = (ko >= 120) ? (ko + 120) : ko;
    bf16x8 av[4];
#pragma unroll
    for (int tf = 0; tf < 4; ++tf)
      av[tf] = *(const bf16x8*)&Xs[xswz(tf * 16 + col, kz)];
#pragma unroll
    for (int st = 0; st < 3; ++st) {
      bf16x8 b = *(const bf16x8*)(W2 + ((wv * 3 + st) * 16 + col) * 128 + ks * 32 + kq);
#pragma unroll
      for (int tf = 0; tf < 4; ++tf)
        acc2[tf][st] = __builtin_amdgcn_mfma_f32_16x16x32_bf16(av[tf], b, acc2[tf][st], 0, 0, 0);
    }
  }
  __builtin_amdgcn_s_setprio(0);

  if (wv >= 5) {
#pragma unroll
    for (int st = 0; st < 3; ++st) {
      const int tile = wv * 3 + st;
      if (tile < 23) {
        const int s = tile * 16 + col;
        const int r = s - 240;
        if (r < 120) {
          const float b2 = bias2[s];
#pragma unroll
          for (int tf = 0; tf < 4; ++tf) {
#pragma unroll
            for (int reg = 0; reg < 4; ++reg) {
              const int t = tf * 16 + quad * 4 + reg;
              const float old = bf2f((unsigned short)Xs[xswz(t, 120 + r)]);
              res_out[((size_t)(bb * L_ + t0 + t)) * 128 + r] =
                  f2bf(old + acc2[tf][st][reg] + b2);
            }
          }
        }
      }
    }
  }
  __syncthreads();

  short* SG = Xs;
  if (wv < 5) {
#pragma unroll
    for (int st = 0; st < 3; ++st) {
      const int tile = wv * 3 + st;
      const int s = tile * 16 + col;
      const float b2 = bias2[s];
#pragma unroll
      for (int tf = 0; tf < 4; ++tf)
#pragma unroll
        for (int reg = 0; reg < 4; ++reg)
          SG[(tf * 16 + quad * 4 + reg) * SGP + s] = f2bf(acc2[tf][st][reg] + b2);
    }
  }
  __syncthreads();

#pragma unroll
  for (int it = 0; it < 4; ++it) {
    const int idx = tid + it * 512;
    if (idx < 1920) {
      const int row = idx / 30;
      const int j = idx - row * 30;
      unsigned short* gp = skips + srow + row * 240 + j * 8;
      int4 sv = *(const int4*)&SG[row * SGP + j * 8];
      const unsigned short* svp = (const unsigned short*)&sv;
      float vals[8];
#pragma unroll
      for (int e = 0; e < 8; ++e) vals[e] = bf2f(svp[e]);
      if (!first) {
        const int4 ov = (it == 0) ? sk0 : (it == 1) ? sk1 : (it == 2) ? sk2 : sk3;
        const unsigned short* ovp = (const unsigned short*)&ov;
#pragma unroll
        for (int e = 0; e < 8; ++e) vals[e] += bf2f(ovp[e]);
      }
      int4 res;
      unsigned short* rp = (unsigned short*)&res;
#pragma unroll
      for (int e = 0; e < 8; ++e) rp[e] = (unsigned short)f2bf(vals[e]);
      *(int4*)gp = res;
    }
  }
}

// ---------------------------------------------------------------------------
// LAYER 15 + HEAD fused (R8). d=128. Differences vs block_mfma_kernel:
//  - no res_out write (residuals after last block are discarded by ref):
//    -15.25 MB + phaseA gone.
//  - G2 computes only the 15 skip tiles (2/wave, acc2[4][2]): -1/3 MFMA.
//  - SG staged at stride SGP2=264 = head A-layout; skips RMW is IN-PLACE in
//    LDS (read partial, add old, relu, write back same slot): no skips
//    global write (-30.5 MB) and no head skips read (-30.5 MB).
//  - h1 -> relu -> h2 -> out inline (2 q-tiles/wave at 512 threads).
// relu(round(x)) == round-then-sign-zero for all cases -> absmax unchanged.
// ---------------------------------------------------------------------------
__global__ __launch_bounds__(512, 4) void block_mfma_last_kernel(
    const short* __restrict__ res_in,
    const unsigned short* __restrict__ skips, const short* __restrict__ condb,
    const short* __restrict__ W1, const short* __restrict__ W2,
    const float* __restrict__ bias1, const float* __restrict__ bias2,
    const short* __restrict__ Wh1, const short* __restrict__ Wh2,
    const float* __restrict__ bh1, const float* __restrict__ bh2,
    float* __restrict__ out)
{
  __shared__ __align__(16) short Xs[64 * KP1];   // 40960 B; SG/Sh overlay

  const int tid = threadIdx.x;
  const int w_id = blockIdx.y * NTILE + blockIdx.x;
  const int nid  = (w_id & 7) * CPX + (w_id >> 3);
  const int bb   = nid / NTILE;
  const int t0   = (nid - bb * NTILE) * 64;

  // ---- stage (d = 128): two tap windows ----
  for (int idx = tid; idx < 128 * 15; idx += 512) {
    const int rr = idx / 15, c8 = idx - rr * 15;
    const int ts = (rr < 64) ? (t0 - 128 + rr) : (t0 + rr - 64);
    int4 v = make_int4(0, 0, 0, 0);
    if (ts >= 0)
      v = *(const int4*)(res_in + ((size_t)(bb * L_ + ts) * 128 + c8 * 8));
    if (rr < 64)
      *(int4*)&Xs[xswz(rr, c8 * 8)] = v;                 // tap0
    const int r1 = rr - 64;
    if (r1 >= 0)
      *(int4*)&Xs[xswz(r1, 120 + c8 * 8)] = v;           // tap1
  }
  for (int idx = tid; idx < 640; idx += 512) {
    const int c = idx % 10, trw = idx / 10;
    const int4 v = *(const int4*)(condb + ((size_t)(bb * L_ + t0 + trw) * M_ + c * 8));
    *(int4*)&Xs[xswz(trw, 240 + c * 8)] = v;
  }
  __syncthreads();

  const int lane = tid & 63;
  const int wv = tid >> 6;
  const int col = lane & 15;
  const int quad = lane >> 4;
  const int kq = quad * 8;

  // ---- GEMM1 ----
  f32x4 acc[4][2];
#pragma unroll
  for (int a = 0; a < 4; ++a)
#pragma unroll
    for (int b = 0; b < 2; ++b) acc[a][b] = (f32x4)(0.f);
  __builtin_amdgcn_s_setprio(1);
#pragma unroll
  for (int ks = 0; ks < 10; ++ks) {
    bf16x8 av[4];
#pragma unroll
    for (int tf = 0; tf < 4; ++tf)
      av[tf] = *(const bf16x8*)&Xs[xswz(tf * 16 + col, ks * 32 + kq)];
#pragma unroll
    for (int ct = 0; ct < 2; ++ct) {
      const int cpt = ((ct == 0) ? wv : (wv + 8)) * 16 + col;
      bf16x8 b = *(const bf16x8*)(W1 + cpt * 320 + ks * 32 + kq);
#pragma unroll
      for (int tf = 0; tf < 4; ++tf)
        acc[tf][ct] = __builtin_amdgcn_mfma_f32_16x16x32_bf16(av[tf], b, acc[tf][ct], 0, 0, 0);
    }
  }
  __builtin_amdgcn_s_setprio(0);
  __syncthreads();

  // ---- gating -> Zs in tap0 bytes ----
  {
    const int ch = wv * 16 + col;
    if (ch < 120) {
      const float bf_ = bias1[ch];
      const float bg_ = bias1[128 + ch];
#pragma unroll
      for (int tf = 0; tf < 4; ++tf) {
#pragma unroll
        for (int reg = 0; reg < 4; ++reg) {
          float f = acc[tf][0][reg] + bf_;
          float g = acc[tf][1][reg] + bg_;
          f = fminf(fmaxf(f, -15.f), 15.f);
          g = fminf(fmaxf(g, -15.f), 15.f);
          const float ef = __expf(2.0f * f);
          const float th = (ef - 1.0f) * __builtin_amdgcn_rcpf(ef + 1.0f);
          const float eg = __expf(-g);
          const float sg = __builtin_amdgcn_rcpf(1.0f + eg);
          const int t = tf * 16 + quad * 4 + reg;
          Xs[xswz(t, ch)] = f2bf(th * sg);
        }
      }
    }
  }
  if (tid < 64)
    *(int4*)&Xs[xswz(tid, 240)] = make_int4(0, 0, 0, 0);
  __syncthreads();

  // ---- skips old-value prefetch (layer 15 always has old values) ----
  const size_t srow = ((size_t)bb * L_ + t0) * 240;
  int4 sk0, sk1, sk2, sk3 = make_int4(0,0,0,0);
  { const int idx = tid;        const int row = idx / 30, j = idx - row * 30;
    sk0 = *(const int4*)(skips + srow + row * 240 + j * 8); }
  { const int idx = tid + 512;  const int row = idx / 30, j = idx - row * 30;
    sk1 = *(const int4*)(skips + srow + row * 240 + j * 8); }
  { const int idx = tid + 1024; const int row = idx / 30, j = idx - row * 30;
    sk2 = *(const int4*)(skips + srow + row * 240 + j * 8); }
  if (tid + 1536 < 1920) {
    const int idx = tid + 1536; const int row = idx / 30, j = idx - row * 30;
    sk3 = *(const int4*)(skips + srow + row * 240 + j * 8); }

  // ---- GEMM2: skip tiles only (tile = wv*2+st < 15) ----
  f32x4 acc2[4][2];
#pragma unroll
  for (int a = 0; a < 4; ++a)
#pragma unroll
    for (int b = 0; b < 2; ++b) acc2[a][b] = (f32x4)(0.f);
  __builtin_amdgcn_s_setprio(1);
#pragma unroll
  for (int ks = 0; ks < 4; ++ks) {
    const int ko = ks * 32 + kq;
    const int kz = (ko >= 120) ? (ko + 120) : ko;
    bf16x8 av[4];
#pragma unroll
    for (int tf = 0; tf < 4; ++tf)
      av[tf] = *(const bf16x8*)&Xs[xswz(tf * 16 + col, kz)];
#pragma unroll
    for (int st = 0; st < 2; ++st) {
      const int tile = wv * 2 + st;
      if (tile < 15) {
        bf16x8 b = *(const bf16x8*)(W2 + (tile * 16 + col) * 128 + ks * 32 + kq);
#pragma unroll
        for (int tf = 0; tf < 4; ++tf)
          acc2[tf][st] = __builtin_amdgcn_mfma_f32_16x16x32_bf16(av[tf], b, acc2[tf][st], 0, 0, 0);
      }
    }
  }
  __builtin_amdgcn_s_setprio(0);
  __syncthreads();   // all Zs reads done -> SG overlay legal

  // ---- SG stage at head stride (SGP2=264); zero pad cols 240..255 ----
  short* SG = Xs;
#pragma unroll
  for (int st = 0; st < 2; ++st) {
    const int tile = wv * 2 + st;
    if (tile < 15) {
      const int s = tile * 16 + col;
      const float b2 = bias2[s];
#pragma unroll
      for (int tf = 0; tf < 4; ++tf)
#pragma unroll
        for (int reg = 0; reg < 4; ++reg)
          SG[(tf * 16 + quad * 4 + reg) * SGP2 + s] = f2bf(acc2[tf][st][reg] + b2);
    }
  }
  if (tid < 128) {
    const int row = tid >> 1, g = tid & 1;
    *(int4*)&SG[row * SGP2 + 240 + g * 8] = make_int4(0, 0, 0, 0);
  }
  __syncthreads();

  // ---- in-place RMW + relu: SG[row][j*8..+7] = relu(SG + old) ----
#pragma unroll
  for (int it = 0; it < 4; ++it) {
    const int idx = tid + it * 512;
    if (idx < 1920) {
      const int row = idx / 30;
      const int j = idx - row * 30;
      short* lp = &SG[row * SGP2 + j * 8];
      int4 sv = *(const int4*)lp;
      const unsigned short* svp = (const unsigned short*)&sv;
      const int4 ov = (it == 0) ? sk0 : (it == 1) ? sk1 : (it == 2) ? sk2 : sk3;
      const unsigned short* ovp = (const unsigned short*)&ov;
      int4 res;
      unsigned short* rp = (unsigned short*)&res;
#pragma unroll
      for (int e = 0; e < 8; ++e)
        rp[e] = (unsigned short)f2bf(fmaxf(bf2f(svp[e]) + bf2f(ovp[e]), 0.0f));
      *(int4*)lp = res;
    }
  }
  __syncthreads();

  // ---- h1 GEMM (K=256): q-tile = wv*2+ct ----
  f32x4 acc1[4][2];
#pragma unroll
  for (int a = 0; a < 4; ++a)
#pragma unroll
    for (int b = 0; b < 2; ++b) acc1[a][b] = (f32x4)(0.f);
  __builtin_amdgcn_s_setprio(1);
#pragma unroll
  for (int ks = 0; ks < 8; ++ks) {
    bf16x8 av[4];
#pragma unroll
    for (int tf = 0; tf < 4; ++tf)
      av[tf] = *(const bf16x8*)&SG[(tf * 16 + col) * SGP2 + ks * 32 + kq];
#pragma unroll
    for (int ct = 0; ct < 2; ++ct) {
      bf16x8 b = *(const bf16x8*)(Wh1 + ((wv * 2 + ct) * 16 + col) * 256 + ks * 32 + kq);
#pragma unroll
      for (int tf = 0; tf < 4; ++tf)
        acc1[tf][ct] = __builtin_amdgcn_mfma_f32_16x16x32_bf16(av[tf], b, acc1[tf][ct], 0, 0, 0);
    }
  }
  __builtin_amdgcn_s_setprio(0);
  __syncthreads();   // SG reads done -> H overlay legal

#pragma unroll
  for (int ct = 0; ct < 2; ++ct) {
    const int q = (wv * 2 + ct) * 16 + col;
    const float b1 = bh1[q];
#pragma unroll
    for (int tf = 0; tf < 4; ++tf)
#pragma unroll
      for (int reg = 0; reg < 4; ++reg)
        SG[(tf * 16 + quad * 4 + reg) * SGP2 + q] = f2bf(fmaxf(acc1[tf][ct][reg] + b1, 0.0f));
  }
  __syncthreads();

  // ---- h2 GEMM (K=256) -> out ----
  f32x4 acc2h[4][2];
#pragma unroll
  for (int a = 0; a < 4; ++a)
#pragma unroll
    for (int b = 0; b < 2; ++b) acc2h[a][b] = (f32x4)(0.f);
  __builtin_amdgcn_s_setprio(1);
#pragma unroll
  for (int ks = 0; ks < 8; ++ks) {
    bf16x8 av[4];
#pragma unroll
    for (int tf = 0; tf < 4; ++tf)
      av[tf] = *(const bf16x8*)&SG[(tf * 16 + col) * SGP2 + ks * 32 + kq];
#pragma unroll
    for (int ct = 0; ct < 2; ++ct) {
      bf16x8 b = *(const bf16x8*)(Wh2 + ((wv * 2 + ct) * 16 + col) * 256 + ks * 32 + kq);
#pragma unroll
      for (int tf = 0; tf < 4; ++tf)
        acc2h[tf][ct] = __builtin_amdgcn_mfma_f32_16x16x32_bf16(av[tf], b, acc2h[tf][ct], 0, 0, 0);
    }
  }
  __builtin_amdgcn_s_setprio(0);
#pragma unroll
  for (int ct = 0; ct < 2; ++ct) {
    const int q = (wv * 2 + ct) * 16 + col;
    const float b2 = bh2[q];
#pragma unroll
    for (int tf = 0; tf < 4; ++tf) {
      const int tg0 = t0 + tf * 16 + quad * 4;
      float4 o = make_float4(acc2h[tf][ct][0] + b2, acc2h[tf][ct][1] + b2,
                             acc2h[tf][ct][2] + b2, acc2h[tf][ct][3] + b2);
      *(float4*)(out + ((size_t)(bb * Q_ + q)) * L_ + tg0) = o;
    }
  }
}

// ---------------------------------------------------------------------------
extern "C" void kernel_launch(void* const* d_in, const int* in_sizes, int n_in,
                              void* d_out, int out_size, void* d_ws, size_t ws_size,
                              hipStream_t stream) {
  const float* wav    = (const float*)d_in[0];
  const float* mel    = (const float*)d_in[1];
  const float* w_up   = (const float*)d_in[2];
  const float* b_up   = (const float*)d_in[3];
  const float* w_in   = (const float*)d_in[4];
  const float* b_in   = (const float*)d_in[5];
  const float* w_gate = (const float*)d_in[6];
  const float* b_gate = (const float*)d_in[7];
  const float* w_cond = (const float*)d_in[8];
  const float* b_cond = (const float*)d_in[9];
  const float* w_res  = (const float*)d_in[10];
  const float* b_res  = (const float*)d_in[11];
  const float* w_skip = (const float*)d_in[12];
  const float* b_skip = (const float*)d_in[13];
  const float* w_h1   = (const float*)d_in[14];
  const float* b_h1   = (const float*)d_in[15];
  const float* w_h2   = (const float*)d_in[16];
  const float* b_h2   = (const float*)d_in[17];
  float* out = (float*)d_out;

  char* w = (char*)d_ws;
  short* condb   = (short*)w;                 w += (size_t)B_ * L_ * M_ * 2;
  short* res0    = (short*)w;                 w += (size_t)B_ * L_ * 128 * 2;
  short* res1    = (short*)w;                 w += (size_t)B_ * L_ * 128 * 2;
  unsigned short* skips = (unsigned short*)w; w += (size_t)B_ * L_ * 240 * 2;
  short* W1p     = (short*)w;                 w += (size_t)16 * 256 * 320 * 2;
  short* W2p     = (short*)w;                 w += (size_t)16 * 384 * 128 * 2;
  short* Wh1p    = (short*)w;                 w += (size_t)256 * 256 * 2;
  short* Wh2p    = (short*)w;                 w += (size_t)256 * 256 * 2;
  float* bias1p  = (float*)w;                 w += (size_t)16 * 256 * 4;
  float* bias2p  = (float*)w;                 w += (size_t)16 * 384 * 4;
  short* melT    = (short*)w;                 w += (size_t)B_ * TMEL * M_ * 2;
  // Wup (13.1 MB) overlays skips: consumed before first block kernel.
  short* Wup = (short*)skips;

  prepack_w1_kernel<<<(16 * 256 * 320) / 256, 256, 0, stream>>>(w_gate, w_cond, W1p);
  prepack_w2_kernel<<<(16 * 384 * 128) / 256, 256, 0, stream>>>(w_skip, w_res, W2p);
  prepack_rest_kernel<<<141312 / 256, 256, 0, stream>>>(
      w_h1, w_h2, b_gate, b_cond, b_skip, b_res, Wh1p, Wh2p, bias1p, bias2p);
  prep_melT_kernel<<<(B_ * TMEL * M_ + 255) / 256, 256, 0, stream>>>(mel, melT);
  prep_wup_kernel<<<80 * 4 * 4, 256, 0, stream>>>(w_up, Wup);

  dim3 ugrid(256, 4);
  upsample_mfma_kernel<<<ugrid, 256, 0, stream>>>(melT, Wup, b_up, condb);
  in_conv_kernel<<<((size_t)B_ * L_ * 128) / 256, 256, 0, stream>>>(wav, w_in, b_in, res0);

  dim3 bgrid(NTILE, B_);
  for (int i = 0; i < NB_ - 1; ++i) {
    const int d = 1 << (i & 7);
    const short* rin  = (i & 1) ? res1 : res0;
    short*       rout = (i & 1) ? res0 : res1;
    block_mfma_kernel<<<bgrid, 512, 0, stream>>>(
        rin, rout, skips, condb,
        W1p + (size_t)i * 256 * 320, W2p + (size_t)i * 384 * 128,
        bias1p + i * 256, bias2p + i * 384,
        d, (i == 0) ? 1 : 0);
  }
  // layer 15 (d=128, reads res1) fused with head
  block_mfma_last_kernel<<<bgrid, 512, 0, stream>>>(
      res1, skips, condb,
      W1p + (size_t)15 * 256 * 320, W2p + (size_t)15 * 384 * 128,
      bias1p + 15 * 256, bias2p + 15 * 384,
      Wh1p, Wh2p, b_h1, b_h2, out);
}